// Round 2
// baseline (499.327 us; speedup 1.0000x reference)
//
#include <hip/hip_runtime.h>
#include <math.h>

typedef __bf16 bf16;
typedef __attribute__((ext_vector_type(8))) __bf16 bf16x8;
typedef __attribute__((ext_vector_type(4))) __bf16 bf16x4;
typedef __attribute__((ext_vector_type(4))) float f32x4;

#define BB 2
#define TT 2048
#define DD 1024
#define NHD 16
#define HD 64
#define MM (BB*TT)          // 4096
#define LOG2E_F 1.442695041f
#define NEGINF_F (-1.0e9f)

// async global->LDS, 16B per lane; LDS dest must be wave-uniform base
__device__ __forceinline__ void gld16(const bf16* g, bf16* l)
{
    __builtin_amdgcn_global_load_lds(
        (const __attribute__((address_space(1))) unsigned int*)g,
        (__attribute__((address_space(3))) unsigned int*)l, 16, 0, 0);
}

// ---------------------------------------------------------------------------
// fused prep: [0,4096) split_x; [4096,8192) weight transpose/convert;
// [8192,12288) mask -> byte-packed bits (8 ints -> 1 byte per thread).
// ---------------------------------------------------------------------------
__global__ __launch_bounds__(256)
void prep_all(const float* __restrict__ X, const int* __restrict__ m,
              const float* __restrict__ wq, const float* __restrict__ wk,
              const float* __restrict__ wv, const float* __restrict__ wo,
              bf16* __restrict__ Xh, bf16* __restrict__ Xl,
              bf16* __restrict__ qkh, bf16* __restrict__ qkl,
              bf16* __restrict__ vh, bf16* __restrict__ ob,
              unsigned char* __restrict__ bits)
{
    __shared__ float tile[32][33];
    const int bid = blockIdx.x;
    const int t   = threadIdx.x;

    if (bid < 4096) {                         // split X -> hi/lo
        int i = bid * 256 + t;
        float4 v = ((const float4*)X)[i];
        float f[4] = {v.x, v.y, v.z, v.w};
        bf16x4 h, l;
        #pragma unroll
        for (int j = 0; j < 4; ++j) {
            bf16 hh = (bf16)f[j];
            h[j] = hh;
            l[j] = (bf16)(f[j] - (float)hh);
        }
        *(bf16x4*)(Xh + (size_t)i * 4) = h;
        *(bf16x4*)(Xl + (size_t)i * 4) = l;
        return;
    }
    if (bid < 8192) {                         // weights
        const int idx = bid - 4096;
        const int z   = idx >> 10;            // 0:wq 1:wk 2:wv 3:wo
        const int bx  = (idx & 31) << 5;      // nh block
        const int by  = ((idx >> 5) & 31) << 5;  // d block
        const int r   = t >> 3;
        const int c4  = (t & 7) << 2;
        if (z == 3) {
            float4 v = *(const float4*)(wo + (size_t)(by + r) * 1024 + bx + c4);
            bf16x4 o = { (bf16)v.x, (bf16)v.y, (bf16)v.z, (bf16)v.w };
            *(bf16x4*)(ob + (size_t)(by + r) * 1024 + bx + c4) = o;
            return;
        }
        const float* src = (z == 0) ? wq : ((z == 1) ? wk : wv);
        bf16* oh = (z == 0) ? qkh : ((z == 1) ? qkh + 1048576 : vh);
        bf16* ol = (z == 0) ? qkl : ((z == 1) ? qkl + 1048576 : nullptr);
        float4 v = *(const float4*)(src + (size_t)(by + r) * 1024 + bx + c4);
        tile[r][c4+0] = v.x; tile[r][c4+1] = v.y;
        tile[r][c4+2] = v.z; tile[r][c4+3] = v.w;
        __syncthreads();
        bf16x4 hv, lv;
        #pragma unroll
        for (int j = 0; j < 4; ++j) {
            float f = tile[c4 + j][r];
            bf16 h = (bf16)f;
            hv[j] = h;
            lv[j] = (bf16)(f - (float)h);
        }
        *(bf16x4*)(oh + (size_t)(bx + r) * 1024 + by + c4) = hv;
        if (ol)
            *(bf16x4*)(ol + (size_t)(bx + r) * 1024 + by + c4) = lv;
        return;
    }
    {                                         // pack mask: 8 ints -> 1 byte
        int i = (bid - 8192) * 256 + t;       // i < 1048576
        const int4* mp = (const int4*)m + (size_t)i * 2;
        int4 a  = mp[0];
        int4 b4 = mp[1];
        unsigned v = (a.x  != 0)       | ((a.y  != 0) << 1)
                   | ((a.z  != 0) << 2) | ((a.w  != 0) << 3)
                   | ((b4.x != 0) << 4) | ((b4.y != 0) << 5)
                   | ((b4.z != 0) << 6) | ((b4.w != 0) << 7);
        bits[i] = (unsigned char)v;
    }
}

// ---------------------------------------------------------------------------
// Fused projection GEMM (768 blocks):
//  [0,512): QK — single K-sweep split (Xh*Wh + Xh*Wl + Xl*Wh), 128x128, BK=32;
//           col<1024 -> Q (scaled, exp2-domain), else K; split hi/lo out.
//  [512,768): V — C^T = Wvh · Xh^T, out Vt[b][nh][t] bf16 + bias.
// ---------------------------------------------------------------------------
__global__ __launch_bounds__(256)
void gemm_proj(const bf16* __restrict__ Xh, const bf16* __restrict__ Xl,
               const bf16* __restrict__ Wh, const bf16* __restrict__ Wl,
               const bf16* __restrict__ Wvh,
               const float* __restrict__ bq, const float* __restrict__ bk,
               const float* __restrict__ bv, const float* __restrict__ pds,
               bf16* __restrict__ oQh, bf16* __restrict__ oQl,
               bf16* __restrict__ oKh, bf16* __restrict__ oKl,
               bf16* __restrict__ oVt)
{
    __shared__ bf16 S[4][128 * 32];   // QK: Ah/Al/Bh/Bl ; V: uses S[0],S[2]

    const int bid  = blockIdx.x;
    const int t    = threadIdx.x;
    const int lane = t & 63;
    const int w    = t >> 6;
    const int quad = lane >> 4, l15 = lane & 15;
    const int wm   = (w >> 1) << 6;
    const int wn   = (w & 1)  << 6;

    const int jr0 = ((w * 2 + 0) << 4) + (lane >> 2);
    const int jr1 = ((w * 2 + 1) << 4) + (lane >> 2);
    const int kch = (lane & 3) << 3;
    const int off0 = (w * 2 + 0) * 512;
    const int off1 = (w * 2 + 1) * 512;

    if (bid < 512) {
        // ---------------- QK path ----------------
        const int m0 = (bid >> 4) << 7;
        const int n0 = (bid & 15) << 7;
        bf16* Ah = S[0]; bf16* Al = S[1]; bf16* Bh = S[2]; bf16* Bl = S[3];

        const bf16* pAh0 = Xh + (size_t)(m0 + jr0) * DD + kch;
        const bf16* pAh1 = Xh + (size_t)(m0 + jr1) * DD + kch;
        const bf16* pAl0 = Xl + (size_t)(m0 + jr0) * DD + kch;
        const bf16* pAl1 = Xl + (size_t)(m0 + jr1) * DD + kch;
        const bf16* pBh0 = Wh + (size_t)(n0 + jr0) * DD + kch;
        const bf16* pBh1 = Wh + (size_t)(n0 + jr1) * DD + kch;
        const bf16* pBl0 = Wl + (size_t)(n0 + jr0) * DD + kch;
        const bf16* pBl1 = Wl + (size_t)(n0 + jr1) * DD + kch;

        f32x4 acc[4][4] = {};

        for (int k0 = 0; k0 < DD; k0 += 32) {
            __syncthreads();
            gld16(pAh0 + k0, Ah + off0);  gld16(pAh1 + k0, Ah + off1);
            gld16(pAl0 + k0, Al + off0);  gld16(pAl1 + k0, Al + off1);
            gld16(pBh0 + k0, Bh + off0);  gld16(pBh1 + k0, Bh + off1);
            gld16(pBl0 + k0, Bl + off0);  gld16(pBl1 + k0, Bl + off1);
            __syncthreads();

            bf16x8 ah[4], bh[4];
            #pragma unroll
            for (int mt = 0; mt < 4; ++mt)
                ah[mt] = *(const bf16x8*)(Ah + (wm + (mt << 4) + l15) * 32 + (quad << 3));
            #pragma unroll
            for (int nt = 0; nt < 4; ++nt)
                bh[nt] = *(const bf16x8*)(Bh + (wn + (nt << 4) + l15) * 32 + (quad << 3));
            #pragma unroll
            for (int mt = 0; mt < 4; ++mt)
                #pragma unroll
                for (int nt = 0; nt < 4; ++nt)
                    acc[mt][nt] = __builtin_amdgcn_mfma_f32_16x16x32_bf16(
                        ah[mt], bh[nt], acc[mt][nt], 0, 0, 0);

            bf16x8 bl[4];
            #pragma unroll
            for (int nt = 0; nt < 4; ++nt)
                bl[nt] = *(const bf16x8*)(Bl + (wn + (nt << 4) + l15) * 32 + (quad << 3));
            #pragma unroll
            for (int mt = 0; mt < 4; ++mt)
                #pragma unroll
                for (int nt = 0; nt < 4; ++nt)
                    acc[mt][nt] = __builtin_amdgcn_mfma_f32_16x16x32_bf16(
                        ah[mt], bl[nt], acc[mt][nt], 0, 0, 0);

            bf16x8 al[4];
            #pragma unroll
            for (int mt = 0; mt < 4; ++mt)
                al[mt] = *(const bf16x8*)(Al + (wm + (mt << 4) + l15) * 32 + (quad << 3));
            #pragma unroll
            for (int mt = 0; mt < 4; ++mt)
                #pragma unroll
                for (int nt = 0; nt < 4; ++nt)
                    acc[mt][nt] = __builtin_amdgcn_mfma_f32_16x16x32_bf16(
                        al[mt], bh[nt], acc[mt][nt], 0, 0, 0);
        }

        #pragma unroll
        for (int nt = 0; nt < 4; ++nt) {
            const int col = n0 + wn + (nt << 4) + l15;
            const int isQ = (col < 1024);
            const int nh  = col & 1023;
            const int n   = nh >> 6, h = nh & 63;
            const float bcol = isQ ? bq[nh] : bk[nh];
            float s = 1.f;
            if (isQ) {
                float x  = pds[h];
                float sp = fmaxf(x, 0.f) + log1pf(expf(-fabsf(x)));  // softplus
                s = (LOG2E_F * LOG2E_F / 8.0f) * sp;  // exp2 domain
            }
            bf16* dH = isQ ? oQh : oKh;
            bf16* dL = isQ ? oQl : oKl;
            #pragma unroll
            for (int mt = 0; mt < 4; ++mt) {
                #pragma unroll
                for (int reg = 0; reg < 4; ++reg) {
                    const int row = m0 + wm + (mt << 4) + (quad << 2) + reg;
                    const int bi  = row >> 11;
                    const int tt  = row & (TT - 1);
                    float val = (acc[mt][nt][reg] + bcol) * s;
                    const size_t idx = (((size_t)bi * NHD + n) * TT + tt) * HD + h;
                    bf16 hi = (bf16)val;
                    dH[idx] = hi;
                    dL[idx] = (bf16)(val - (float)hi);
                }
            }
        }
    } else {
        // ---------------- V path ----------------
        const int idx = bid - 512;
        const int m0  = (idx >> 5) << 7;      // nh tile (8)
        const int n0  = (idx & 31) << 7;      // bt tile (32)
        bf16* As = S[0]; bf16* Bs = S[2];

        const bf16* Ap0 = Wvh + (size_t)(m0 + jr0) * DD + kch;
        const bf16* Ap1 = Wvh + (size_t)(m0 + jr1) * DD + kch;
        const bf16* Bp0 = Xh  + (size_t)(n0 + jr0) * DD + kch;
        const bf16* Bp1 = Xh  + (size_t)(n0 + jr1) * DD + kch;

        f32x4 acc[4][4] = {};

        for (int k0 = 0; k0 < DD; k0 += 32) {
            __syncthreads();
            gld16(Ap0 + k0, As + off0);
            gld16(Ap1 + k0, As + off1);
            gld16(Bp0 + k0, Bs + off0);
            gld16(Bp1 + k0, Bs + off1);
            __syncthreads();
            bf16x8 af[4], bfm[4];
            #pragma unroll
            for (int mt = 0; mt < 4; ++mt)
                af[mt] = *(const bf16x8*)(As + (wm + (mt << 4) + l15) * 32 + (quad << 3));
            #pragma unroll
            for (int nt = 0; nt < 4; ++nt)
                bfm[nt] = *(const bf16x8*)(Bs + (wn + (nt << 4) + l15) * 32 + (quad << 3));
            #pragma unroll
            for (int mt = 0; mt < 4; ++mt)
                #pragma unroll
                for (int nt = 0; nt < 4; ++nt)
                    acc[mt][nt] = __builtin_amdgcn_mfma_f32_16x16x32_bf16(
                        af[mt], bfm[nt], acc[mt][nt], 0, 0, 0);
        }

        #pragma unroll
        for (int nt = 0; nt < 4; ++nt) {
            const int col = n0 + wn + (nt << 4) + l15;   // bt
            const int bi  = col >> 11;
            const int tt  = col & (TT - 1);
            #pragma unroll
            for (int mt = 0; mt < 4; ++mt) {
                #pragma unroll
                for (int reg = 0; reg < 4; ++reg) {
                    const int row = m0 + wm + (mt << 4) + (quad << 2) + reg;  // nh
                    float val = acc[mt][nt][reg] + bv[row];
                    oVt[((size_t)bi * 1024 + row) * TT + tt] = (bf16)val;
                }
            }
        }
    }
}

// ---------------------------------------------------------------------------
// Output projection GEMM: 128x64 tile, 512 blocks (2/CU), BK=32, fp32 out.
// ---------------------------------------------------------------------------
__global__ __launch_bounds__(256)
void gemm_out(const bf16* __restrict__ A, const bf16* __restrict__ Bt,
              const float* __restrict__ bias, float* __restrict__ oF)
{
    __shared__ bf16 As[128 * 32];
    __shared__ bf16 Bs[64 * 32];

    const int t    = threadIdx.x;
    const int lane = t & 63;
    const int w    = t >> 6;
    const int quad = lane >> 4, l15 = lane & 15;
    const int m0   = blockIdx.y << 7;
    const int n0   = blockIdx.x << 6;
    const int wm   = (w >> 1) << 6;
    const int wn   = (w & 1)  << 5;

    const int jr0 = ((w * 2 + 0) << 4) + (lane >> 2);
    const int jr1 = ((w * 2 + 1) << 4) + (lane >> 2);
    const int jrB = (w << 4) + (lane >> 2);
    const int kch = (lane & 3) << 3;

    bf16* lA0 = As + (w * 2 + 0) * 512;
    bf16* lA1 = As + (w * 2 + 1) * 512;
    bf16* lB  = Bs + w * 512;

    const bf16* Ap0 = A  + (size_t)(m0 + jr0) * DD + kch;
    const bf16* Ap1 = A  + (size_t)(m0 + jr1) * DD + kch;
    const bf16* Bp  = Bt + (size_t)(n0 + jrB) * DD + kch;

    f32x4 acc[4][2] = {};

    for (int k0 = 0; k0 < DD; k0 += 32) {
        __syncthreads();
        gld16(Ap0 + k0, lA0);
        gld16(Ap1 + k0, lA1);
        gld16(Bp + k0, lB);
        __syncthreads();
        bf16x8 af[4], bfm[2];
        #pragma unroll
        for (int mt = 0; mt < 4; ++mt)
            af[mt] = *(const bf16x8*)(As + (wm + (mt << 4) + l15) * 32 + (quad << 3));
        #pragma unroll
        for (int nt = 0; nt < 2; ++nt)
            bfm[nt] = *(const bf16x8*)(Bs + (wn + (nt << 4) + l15) * 32 + (quad << 3));
        #pragma unroll
        for (int mt = 0; mt < 4; ++mt)
            #pragma unroll
            for (int nt = 0; nt < 2; ++nt)
                acc[mt][nt] = __builtin_amdgcn_mfma_f32_16x16x32_bf16(
                    af[mt], bfm[nt], acc[mt][nt], 0, 0, 0);
    }

    #pragma unroll
    for (int nt = 0; nt < 2; ++nt) {
        const int col = n0 + wn + (nt << 4) + l15;
        const float bcol = bias[col];
        #pragma unroll
        for (int mt = 0; mt < 4; ++mt) {
            #pragma unroll
            for (int reg = 0; reg < 4; ++reg) {
                const int row = m0 + wm + (mt << 4) + (quad << 2) + reg;
                oF[(size_t)row * DD + col] = acc[mt][nt][reg] + bcol;
            }
        }
    }
}

// ---------------------------------------------------------------------------
// MFMA flash attention v3: split-K within block.
// q-tile 64, 512 threads (8 waves). Waves 0-3: k in [0,1024); waves 4-7:
// k in [1024,2048). Each wave owns 16 q rows; the two k-groups merge their
// online-softmax states through LDS at the end.
// V time-shares the K-lo LDS buffer (QK uses Kh+Kl; after a barrier V is
// staged over Kl for the PV phase) -> LDS 49 KB -> 3 blocks/CU, 24 waves/CU
// (was 2 blocks / 16 waves, OccupancyPercent 36).
// XOR-swizzled 16B chunks on write+read (T2), setprio (T5), defer-max (T13).
// ---------------------------------------------------------------------------
__global__ __launch_bounds__(512, 6)
void attn_mfma(const bf16* __restrict__ Qh, const bf16* __restrict__ Ql,
               const bf16* __restrict__ Kh, const bf16* __restrict__ Kl,
               const bf16* __restrict__ Vt,
               const unsigned long long* __restrict__ mb64,
               bf16* __restrict__ AO)
{
    __shared__ bf16 KH[2][64 * 64];    // K-hi per k-group
    __shared__ bf16 KL[2][64 * 64];    // K-lo, later V (time-shared)
    __shared__ bf16 PS[8][16 * 64];    // per-wave P, swizzled
    __shared__ unsigned long long MSK[2][64];

    const int t    = threadIdx.x;
    const int lane = t & 63;
    const int w    = t >> 6;           // 0..7
    const int g    = w >> 2;           // k-group 0/1
    const int quad = lane >> 4, l15 = lane & 15;
    const int bn   = blockIdx.y;
    const int b    = bn >> 4, n = bn & 15;
    const int q0   = blockIdx.x << 6;  // 64 q per block

    const bf16* Qbh = Qh + (size_t)bn * TT * HD;
    const bf16* Qbl = Ql + (size_t)bn * TT * HD;
    const bf16* Kbh = Kh + (size_t)bn * TT * HD;
    const bf16* Kbl = Kl + (size_t)bn * TT * HD;
    const bf16* Vtb = Vt + (size_t)bn * HD * TT;

    // Q fragments (B-operand: n=q=l15, k=h) — registers, loaded once
    const int qrow = q0 + ((w & 3) << 4) + l15;
    bf16x8 qfh[2], qfl[2];
    qfh[0] = *(const bf16x8*)(Qbh + (size_t)qrow * HD + (quad << 3));
    qfh[1] = *(const bf16x8*)(Qbh + (size_t)qrow * HD + 32 + (quad << 3));
    qfl[0] = *(const bf16x8*)(Qbl + (size_t)qrow * HD + (quad << 3));
    qfl[1] = *(const bf16x8*)(Qbl + (size_t)qrow * HD + 32 + (quad << 3));

    f32x4 O[4];                         // O^T: row h=nt*16+quad*4+reg, col q=l15
    #pragma unroll
    for (int i = 0; i < 4; ++i) O[i] = (f32x4){0.f,0.f,0.f,0.f};
    float m_i = -INFINITY;
    float l_i = 0.f;

    // group-local staging map: 256 threads cover 64 rows x 8 chunks (2 each)
    const int tg  = t & 255;
    const int rS  = tg >> 2;                         // 0..63
    const int cp  = tg & 3;                          // chunk pair
    const int cG0 = (cp * 2    ) << 3;
    const int cG1 = (cp * 2 + 1) << 3;
    const int cL0 = (((cp * 2    ) ^ (rS & 7))) << 3;  // swizzled LDS chunk
    const int cL1 = (((cp * 2 + 1) ^ (rS & 7))) << 3;
    // fragment-read swizzle key: row&7 == l15&7 for row = nt*16+l15
    const int sw8 = (l15 & 7) << 3;

    for (int it = 0; it < 16; ++it) {
        const int kb = (g << 10) + (it << 6);
        // prefetch globals into regs
        const bf16* kr = Kbh + (size_t)(kb + rS) * HD;
        const bf16* lr = Kbl + (size_t)(kb + rS) * HD;
        const bf16* vr = Vtb + (size_t)rS * TT + kb;
        bf16x8 kh0 = *(const bf16x8*)(kr + cG0);
        bf16x8 kh1 = *(const bf16x8*)(kr + cG1);
        bf16x8 kl0 = *(const bf16x8*)(lr + cG0);
        bf16x8 kl1 = *(const bf16x8*)(lr + cG1);
        bf16x8 v0  = *(const bf16x8*)(vr + cG0);
        bf16x8 v1  = *(const bf16x8*)(vr + cG1);
        unsigned long long mw = 0;
        if (t < 128)
            mw = mb64[((size_t)b * TT + q0 + (t & 63)) * (TT / 64)
                      + ((t >> 6) << 4) + it];

        __syncthreads();   // B1: previous tile fully consumed
        *(bf16x8*)&KH[g][rS * 64 + cL0] = kh0;
        *(bf16x8*)&KH[g][rS * 64 + cL1] = kh1;
        *(bf16x8*)&KL[g][rS * 64 + cL0] = kl0;
        *(bf16x8*)&KL[g][rS * 64 + cL1] = kl1;
        if (t < 128) MSK[t >> 6][t & 63] = mw;
        __syncthreads();   // B2: K tiles + mask visible

        // S^T = K Q^T (rows s, cols q), split: Kh*Qh + Kl*Qh + Kh*Ql
        f32x4 s_acc[4];
        #pragma unroll
        for (int i = 0; i < 4; ++i) s_acc[i] = (f32x4){0.f,0.f,0.f,0.f};
        __builtin_amdgcn_s_setprio(1);
        #pragma unroll
        for (int k2 = 0; k2 < 2; ++k2) {
            #pragma unroll
            for (int nt = 0; nt < 4; ++nt) {
                const int ro = ((nt << 4) + l15) * 64;
                const int co = ((k2 << 5) + (quad << 3)) ^ sw8;
                bf16x8 bkh = *(const bf16x8*)&KH[g][ro + co];
                bf16x8 bkl = *(const bf16x8*)&KL[g][ro + co];
                s_acc[nt] = __builtin_amdgcn_mfma_f32_16x16x32_bf16(bkh, qfh[k2], s_acc[nt], 0, 0, 0);
                s_acc[nt] = __builtin_amdgcn_mfma_f32_16x16x32_bf16(bkl, qfh[k2], s_acc[nt], 0, 0, 0);
                s_acc[nt] = __builtin_amdgcn_mfma_f32_16x16x32_bf16(bkh, qfl[k2], s_acc[nt], 0, 0, 0);
            }
        }
        __builtin_amdgcn_s_setprio(0);

        // per-lane softmax over s (16 local vals + cross-quad shuffles)
        const unsigned long long word = MSK[g][((w & 3) << 4) + l15];
        const unsigned w0 = (unsigned)word;
        const unsigned w1 = (unsigned)(word >> 32);
        float sv[16];
        #pragma unroll
        for (int nt = 0; nt < 4; ++nt) {
            const unsigned wrd = (nt & 2) ? w1 : w0;
            #pragma unroll
            for (int reg = 0; reg < 4; ++reg) {
                const int bit = ((nt & 1) << 4) + (quad << 2) + reg;
                sv[nt * 4 + reg] = ((wrd >> bit) & 1u) ? s_acc[nt][reg] : NEGINF_F;
            }
        }
        // tree max
        float a0 = fmaxf(sv[0], sv[1]),  a1 = fmaxf(sv[2], sv[3]);
        float a2 = fmaxf(sv[4], sv[5]),  a3 = fmaxf(sv[6], sv[7]);
        float a4 = fmaxf(sv[8], sv[9]),  a5 = fmaxf(sv[10], sv[11]);
        float a6 = fmaxf(sv[12], sv[13]), a7 = fmaxf(sv[14], sv[15]);
        float b0 = fmaxf(a0, a1), b1 = fmaxf(a2, a3);
        float b2 = fmaxf(a4, a5), b3 = fmaxf(a6, a7);
        float mx = fmaxf(fmaxf(b0, b1), fmaxf(b2, b3));
        mx = fmaxf(mx, __shfl_xor(mx, 16));
        mx = fmaxf(mx, __shfl_xor(mx, 32));

        // T13 defer-max (exp2 domain, THR=8)
        if (!__all(mx <= m_i + 8.0f)) {
            const float mnew  = fmaxf(m_i, mx);
            const float alpha = exp2f(m_i - mnew);   // exp2(-inf)=0 first tile
            l_i *= alpha;
            #pragma unroll
            for (int nt = 0; nt < 4; ++nt) {
                O[nt][0] *= alpha; O[nt][1] *= alpha;
                O[nt][2] *= alpha; O[nt][3] *= alpha;
            }
            m_i = mnew;
        }

        float p[16];
        #pragma unroll
        for (int i = 0; i < 16; ++i) p[i] = exp2f(sv[i] - m_i);
        float s0 = (p[0] + p[1]) + (p[2] + p[3]);
        float s1 = (p[4] + p[5]) + (p[6] + p[7]);
        float s2 = (p[8] + p[9]) + (p[10] + p[11]);
        float s3 = (p[12] + p[13]) + (p[14] + p[15]);
        float sum = (s0 + s1) + (s2 + s3);
        sum += __shfl_xor(sum, 16);
        sum += __shfl_xor(sum, 32);
        l_i += sum;

        #pragma unroll
        for (int nt = 0; nt < 4; ++nt) {
            bf16x4 pv = { (bf16)p[nt * 4 + 0], (bf16)p[nt * 4 + 1],
                          (bf16)p[nt * 4 + 2], (bf16)p[nt * 4 + 3] };
            *(bf16x4*)&PS[w][l15 * 64 + (((nt << 4) + (quad << 2)) ^ sw8)] = pv;
        }

        __syncthreads();   // B3: all QK reads of KL done -> stage V over it
        *(bf16x8*)&KL[g][rS * 64 + cL0] = v0;
        *(bf16x8*)&KL[g][rS * 64 + cL1] = v1;
        __syncthreads();   // B4: V visible

        // O^T += Vt P^T  (A=Vt rows h, B=P rows q)
        __builtin_amdgcn_s_setprio(1);
        #pragma unroll
        for (int s2i = 0; s2i < 2; ++s2i) {
            bf16x8 ap = *(const bf16x8*)&PS[w][l15 * 64 + (((s2i << 5) + (quad << 3)) ^ sw8)];
            #pragma unroll
            for (int nt = 0; nt < 4; ++nt) {
                bf16x8 bv = *(const bf16x8*)&KL[g][((nt << 4) + l15) * 64
                                                   + (((s2i << 5) + (quad << 3)) ^ sw8)];
                O[nt] = __builtin_amdgcn_mfma_f32_16x16x32_bf16(bv, ap, O[nt], 0, 0, 0);
            }
        }
        __builtin_amdgcn_s_setprio(0);
    }

    // ---- merge the two k-groups (wave w and wave w+4 share 16 q rows) ----
    float* OMp = (float*)&KH[0][0];     // 16 KB = 4096 floats: [w4][h][q16]
    float* MLp = (float*)&KL[0][0];     // m,l pairs
    __syncthreads();                     // all PV reads of KL done
    if (w >= 4) {
        const int base = (w - 4) << 10;
        #pragma unroll
        for (int nt = 0; nt < 4; ++nt)
            #pragma unroll
            for (int reg = 0; reg < 4; ++reg) {
                const int h = (nt << 4) + (quad << 2) + reg;
                OMp[base + h * 16 + l15] = O[nt][reg];
            }
        if (quad == 0) {
            MLp[((w - 4) << 5) + (l15 << 1)    ] = m_i;
            MLp[((w - 4) << 5) + (l15 << 1) + 1] = l_i;
        }
    }
    __syncthreads();
    if (w < 4) {
        const float m1v = MLp[(w << 5) + (l15 << 1)];
        const float l1v = MLp[(w << 5) + (l15 << 1) + 1];
        const float mm  = fmaxf(m_i, m1v);
        const float f0  = exp2f(m_i - mm);
        const float f1  = exp2f(m1v - mm);
        const float inv = 1.0f / (l_i * f0 + l1v * f1);
        const int   ob  = w << 10;
        const size_t basew = ((size_t)b * TT + qrow) * (NHD * HD) + (size_t)n * HD;
        #pragma unroll
        for (int nt = 0; nt < 4; ++nt) {
            bf16x4 o;
            #pragma unroll
            for (int reg = 0; reg < 4; ++reg) {
                const int h = (nt << 4) + (quad << 2) + reg;
                const float o1 = OMp[ob + h * 16 + l15];
                o[reg] = (bf16)((O[nt][reg] * f0 + o1 * f1) * inv);
            }
            *(bf16x4*)(AO + basew + (nt << 4) + (quad << 2)) = o;
        }
    }
}

// ---------------------------------------------------------------------------
extern "C" void kernel_launch(void* const* d_in, const int* in_sizes, int n_in,
                              void* d_out, int out_size, void* d_ws, size_t ws_size,
                              hipStream_t stream)
{
    const float* X   = (const float*)d_in[0];
    const int*   msk = (const int*)d_in[1];
    const float* wq  = (const float*)d_in[2];
    const float* bq  = (const float*)d_in[3];
    const float* wk  = (const float*)d_in[4];
    const float* bk  = (const float*)d_in[5];
    const float* wv  = (const float*)d_in[6];
    const float* bv  = (const float*)d_in[7];
    const float* wo  = (const float*)d_in[8];
    const float* bo  = (const float*)d_in[9];
    const float* pds = (const float*)d_in[10];
    float* out = (float*)d_out;

    bf16* ws   = (bf16*)d_ws;
    bf16* Xh   = ws;                      // 4M  (later aliased by AO)
    bf16* Xl   = ws + 4194304;            // 4M
    bf16* WQKh = ws + 8388608;            // 2M  [2048 nh'][1024 d]
    bf16* WQKl = ws + 10485760;           // 2M
    bf16* Wvh  = ws + 12582912;           // 1M  [nh][d]
    bf16* Wob  = ws + 13631488;           // 1M  [d][nh]
    bf16* Qhb  = ws + 14680064;           // 4M  [b][n][t][h]
    bf16* Qlb  = ws + 18874368;
    bf16* Khb  = ws + 23068672;
    bf16* Klb  = ws + 27262976;
    unsigned char* mbits = (unsigned char*)(ws + 31457280);   // 1 MB
    bf16* Vtb  = ws + 32505856;           // 4M [b][nh][t]
    bf16* AOb  = Xh;                      // alias: Xh dead after proj

    dim3 blk(256);

    prep_all<<<12288, blk, 0, stream>>>(X, msk, wq, wk, wv, wo,
                                        Xh, Xl, WQKh, WQKl, Wvh, Wob, mbits);

    // fused QK + V projections
    gemm_proj<<<768, blk, 0, stream>>>(
        Xh, Xl, WQKh, WQKl, Wvh, bq, bk, bv, pds,
        Qhb, Qlb, Khb, Klb, Vtb);

    dim3 ga(TT / 64, BB * NHD);   // (32, 32) — split-K in-block, q-tile 64
    attn_mfma<<<ga, dim3(512), 0, stream>>>(
        Qhb, Qlb, Khb, Klb, Vtb, (const unsigned long long*)mbits, AOb);

    // output projection: M=4096, N=1024, K=1024, fp32 out, 128x64 tiles
    gemm_out<<<dim3(16, 32), blk, 0, stream>>>(AOb, Wob, bo, out);
}

// Round 3
// 386.445 us; speedup vs baseline: 1.2921x; 1.2921x over previous
//
#include <hip/hip_runtime.h>
#include <math.h>

typedef __bf16 bf16;
typedef __attribute__((ext_vector_type(8))) __bf16 bf16x8;
typedef __attribute__((ext_vector_type(4))) __bf16 bf16x4;
typedef __attribute__((ext_vector_type(4))) float f32x4;

#define BB 2
#define TT 2048
#define DD 1024
#define NHD 16
#define HD 64
#define MM (BB*TT)          // 4096
#define LOG2E_F 1.442695041f
#define NEGINF_F (-1.0e9f)

// async global->LDS, 16B per lane; LDS dest must be wave-uniform base
__device__ __forceinline__ void gld16(const bf16* g, bf16* l)
{
    __builtin_amdgcn_global_load_lds(
        (const __attribute__((address_space(1))) unsigned int*)g,
        (__attribute__((address_space(3))) unsigned int*)l, 16, 0, 0);
}

// ---------------------------------------------------------------------------
// fused prep: [0,4096) split_x; [4096,8192) weight transpose/convert;
// [8192,12288) mask -> byte-packed bits (8 ints -> 1 byte per thread).
// ---------------------------------------------------------------------------
__global__ __launch_bounds__(256)
void prep_all(const float* __restrict__ X, const int* __restrict__ m,
              const float* __restrict__ wq, const float* __restrict__ wk,
              const float* __restrict__ wv, const float* __restrict__ wo,
              bf16* __restrict__ Xh, bf16* __restrict__ Xl,
              bf16* __restrict__ qkh, bf16* __restrict__ qkl,
              bf16* __restrict__ vh, bf16* __restrict__ ob,
              unsigned char* __restrict__ bits)
{
    __shared__ float tile[32][33];
    const int bid = blockIdx.x;
    const int t   = threadIdx.x;

    if (bid < 4096) {                         // split X -> hi/lo
        int i = bid * 256 + t;
        float4 v = ((const float4*)X)[i];
        float f[4] = {v.x, v.y, v.z, v.w};
        bf16x4 h, l;
        #pragma unroll
        for (int j = 0; j < 4; ++j) {
            bf16 hh = (bf16)f[j];
            h[j] = hh;
            l[j] = (bf16)(f[j] - (float)hh);
        }
        *(bf16x4*)(Xh + (size_t)i * 4) = h;
        *(bf16x4*)(Xl + (size_t)i * 4) = l;
        return;
    }
    if (bid < 8192) {                         // weights
        const int idx = bid - 4096;
        const int z   = idx >> 10;            // 0:wq 1:wk 2:wv 3:wo
        const int bx  = (idx & 31) << 5;      // nh block
        const int by  = ((idx >> 5) & 31) << 5;  // d block
        const int r   = t >> 3;
        const int c4  = (t & 7) << 2;
        if (z == 3) {
            float4 v = *(const float4*)(wo + (size_t)(by + r) * 1024 + bx + c4);
            bf16x4 o = { (bf16)v.x, (bf16)v.y, (bf16)v.z, (bf16)v.w };
            *(bf16x4*)(ob + (size_t)(by + r) * 1024 + bx + c4) = o;
            return;
        }
        const float* src = (z == 0) ? wq : ((z == 1) ? wk : wv);
        bf16* oh = (z == 0) ? qkh : ((z == 1) ? qkh + 1048576 : vh);
        bf16* ol = (z == 0) ? qkl : ((z == 1) ? qkl + 1048576 : nullptr);
        float4 v = *(const float4*)(src + (size_t)(by + r) * 1024 + bx + c4);
        tile[r][c4+0] = v.x; tile[r][c4+1] = v.y;
        tile[r][c4+2] = v.z; tile[r][c4+3] = v.w;
        __syncthreads();
        bf16x4 hv, lv;
        #pragma unroll
        for (int j = 0; j < 4; ++j) {
            float f = tile[c4 + j][r];
            bf16 h = (bf16)f;
            hv[j] = h;
            lv[j] = (bf16)(f - (float)h);
        }
        *(bf16x4*)(oh + (size_t)(bx + r) * 1024 + by + c4) = hv;
        if (ol)
            *(bf16x4*)(ol + (size_t)(bx + r) * 1024 + by + c4) = lv;
        return;
    }
    {                                         // pack mask: 8 ints -> 1 byte
        int i = (bid - 8192) * 256 + t;       // i < 1048576
        const int4* mp = (const int4*)m + (size_t)i * 2;
        int4 a  = mp[0];
        int4 b4 = mp[1];
        unsigned v = (a.x  != 0)       | ((a.y  != 0) << 1)
                   | ((a.z  != 0) << 2) | ((a.w  != 0) << 3)
                   | ((b4.x != 0) << 4) | ((b4.y != 0) << 5)
                   | ((b4.z != 0) << 6) | ((b4.w != 0) << 7);
        bits[i] = (unsigned char)v;
    }
}

// ---------------------------------------------------------------------------
// Fused projection GEMM (768 blocks):
//  [0,512): QK — single K-sweep split (Xh*Wh + Xh*Wl + Xl*Wh), 128x128, BK=32;
//           col<1024 -> Q (scaled, exp2-domain), else K; split hi/lo out.
//  [512,768): V — C^T = Wvh · Xh^T, out Vt[b][nh][t] bf16 + bias.
// ---------------------------------------------------------------------------
__global__ __launch_bounds__(256)
void gemm_proj(const bf16* __restrict__ Xh, const bf16* __restrict__ Xl,
               const bf16* __restrict__ Wh, const bf16* __restrict__ Wl,
               const bf16* __restrict__ Wvh,
               const float* __restrict__ bq, const float* __restrict__ bk,
               const float* __restrict__ bv, const float* __restrict__ pds,
               bf16* __restrict__ oQh, bf16* __restrict__ oQl,
               bf16* __restrict__ oKh, bf16* __restrict__ oKl,
               bf16* __restrict__ oVt)
{
    __shared__ bf16 S[4][128 * 32];   // QK: Ah/Al/Bh/Bl ; V: uses S[0],S[2]

    const int bid  = blockIdx.x;
    const int t    = threadIdx.x;
    const int lane = t & 63;
    const int w    = t >> 6;
    const int quad = lane >> 4, l15 = lane & 15;
    const int wm   = (w >> 1) << 6;
    const int wn   = (w & 1)  << 6;

    const int jr0 = ((w * 2 + 0) << 4) + (lane >> 2);
    const int jr1 = ((w * 2 + 1) << 4) + (lane >> 2);
    const int kch = (lane & 3) << 3;
    const int off0 = (w * 2 + 0) * 512;
    const int off1 = (w * 2 + 1) * 512;

    if (bid < 512) {
        // ---------------- QK path ----------------
        const int m0 = (bid >> 4) << 7;
        const int n0 = (bid & 15) << 7;
        bf16* Ah = S[0]; bf16* Al = S[1]; bf16* Bh = S[2]; bf16* Bl = S[3];

        const bf16* pAh0 = Xh + (size_t)(m0 + jr0) * DD + kch;
        const bf16* pAh1 = Xh + (size_t)(m0 + jr1) * DD + kch;
        const bf16* pAl0 = Xl + (size_t)(m0 + jr0) * DD + kch;
        const bf16* pAl1 = Xl + (size_t)(m0 + jr1) * DD + kch;
        const bf16* pBh0 = Wh + (size_t)(n0 + jr0) * DD + kch;
        const bf16* pBh1 = Wh + (size_t)(n0 + jr1) * DD + kch;
        const bf16* pBl0 = Wl + (size_t)(n0 + jr0) * DD + kch;
        const bf16* pBl1 = Wl + (size_t)(n0 + jr1) * DD + kch;

        f32x4 acc[4][4] = {};

        for (int k0 = 0; k0 < DD; k0 += 32) {
            __syncthreads();
            gld16(pAh0 + k0, Ah + off0);  gld16(pAh1 + k0, Ah + off1);
            gld16(pAl0 + k0, Al + off0);  gld16(pAl1 + k0, Al + off1);
            gld16(pBh0 + k0, Bh + off0);  gld16(pBh1 + k0, Bh + off1);
            gld16(pBl0 + k0, Bl + off0);  gld16(pBl1 + k0, Bl + off1);
            __syncthreads();

            bf16x8 ah[4], bh[4];
            #pragma unroll
            for (int mt = 0; mt < 4; ++mt)
                ah[mt] = *(const bf16x8*)(Ah + (wm + (mt << 4) + l15) * 32 + (quad << 3));
            #pragma unroll
            for (int nt = 0; nt < 4; ++nt)
                bh[nt] = *(const bf16x8*)(Bh + (wn + (nt << 4) + l15) * 32 + (quad << 3));
            #pragma unroll
            for (int mt = 0; mt < 4; ++mt)
                #pragma unroll
                for (int nt = 0; nt < 4; ++nt)
                    acc[mt][nt] = __builtin_amdgcn_mfma_f32_16x16x32_bf16(
                        ah[mt], bh[nt], acc[mt][nt], 0, 0, 0);

            bf16x8 bl[4];
            #pragma unroll
            for (int nt = 0; nt < 4; ++nt)
                bl[nt] = *(const bf16x8*)(Bl + (wn + (nt << 4) + l15) * 32 + (quad << 3));
            #pragma unroll
            for (int mt = 0; mt < 4; ++mt)
                #pragma unroll
                for (int nt = 0; nt < 4; ++nt)
                    acc[mt][nt] = __builtin_amdgcn_mfma_f32_16x16x32_bf16(
                        ah[mt], bl[nt], acc[mt][nt], 0, 0, 0);

            bf16x8 al[4];
            #pragma unroll
            for (int mt = 0; mt < 4; ++mt)
                al[mt] = *(const bf16x8*)(Al + (wm + (mt << 4) + l15) * 32 + (quad << 3));
            #pragma unroll
            for (int mt = 0; mt < 4; ++mt)
                #pragma unroll
                for (int nt = 0; nt < 4; ++nt)
                    acc[mt][nt] = __builtin_amdgcn_mfma_f32_16x16x32_bf16(
                        al[mt], bh[nt], acc[mt][nt], 0, 0, 0);
        }

        #pragma unroll
        for (int nt = 0; nt < 4; ++nt) {
            const int col = n0 + wn + (nt << 4) + l15;
            const int isQ = (col < 1024);
            const int nh  = col & 1023;
            const int n   = nh >> 6, h = nh & 63;
            const float bcol = isQ ? bq[nh] : bk[nh];
            float s = 1.f;
            if (isQ) {
                float x  = pds[h];
                float sp = fmaxf(x, 0.f) + log1pf(expf(-fabsf(x)));  // softplus
                s = (LOG2E_F * LOG2E_F / 8.0f) * sp;  // exp2 domain
            }
            bf16* dH = isQ ? oQh : oKh;
            bf16* dL = isQ ? oQl : oKl;
            #pragma unroll
            for (int mt = 0; mt < 4; ++mt) {
                #pragma unroll
                for (int reg = 0; reg < 4; ++reg) {
                    const int row = m0 + wm + (mt << 4) + (quad << 2) + reg;
                    const int bi  = row >> 11;
                    const int tt  = row & (TT - 1);
                    float val = (acc[mt][nt][reg] + bcol) * s;
                    const size_t idx = (((size_t)bi * NHD + n) * TT + tt) * HD + h;
                    bf16 hi = (bf16)val;
                    dH[idx] = hi;
                    dL[idx] = (bf16)(val - (float)hi);
                }
            }
        }
    } else {
        // ---------------- V path ----------------
        const int idx = bid - 512;
        const int m0  = (idx >> 5) << 7;      // nh tile (8)
        const int n0  = (idx & 31) << 7;      // bt tile (32)
        bf16* As = S[0]; bf16* Bs = S[2];

        const bf16* Ap0 = Wvh + (size_t)(m0 + jr0) * DD + kch;
        const bf16* Ap1 = Wvh + (size_t)(m0 + jr1) * DD + kch;
        const bf16* Bp0 = Xh  + (size_t)(n0 + jr0) * DD + kch;
        const bf16* Bp1 = Xh  + (size_t)(n0 + jr1) * DD + kch;

        f32x4 acc[4][4] = {};

        for (int k0 = 0; k0 < DD; k0 += 32) {
            __syncthreads();
            gld16(Ap0 + k0, As + off0);
            gld16(Ap1 + k0, As + off1);
            gld16(Bp0 + k0, Bs + off0);
            gld16(Bp1 + k0, Bs + off1);
            __syncthreads();
            bf16x8 af[4], bfm[4];
            #pragma unroll
            for (int mt = 0; mt < 4; ++mt)
                af[mt] = *(const bf16x8*)(As + (wm + (mt << 4) + l15) * 32 + (quad << 3));
            #pragma unroll
            for (int nt = 0; nt < 4; ++nt)
                bfm[nt] = *(const bf16x8*)(Bs + (wn + (nt << 4) + l15) * 32 + (quad << 3));
            #pragma unroll
            for (int mt = 0; mt < 4; ++mt)
                #pragma unroll
                for (int nt = 0; nt < 4; ++nt)
                    acc[mt][nt] = __builtin_amdgcn_mfma_f32_16x16x32_bf16(
                        af[mt], bfm[nt], acc[mt][nt], 0, 0, 0);
        }

        #pragma unroll
        for (int nt = 0; nt < 4; ++nt) {
            const int col = n0 + wn + (nt << 4) + l15;   // bt
            const int bi  = col >> 11;
            const int tt  = col & (TT - 1);
            #pragma unroll
            for (int mt = 0; mt < 4; ++mt) {
                #pragma unroll
                for (int reg = 0; reg < 4; ++reg) {
                    const int row = m0 + wm + (mt << 4) + (quad << 2) + reg;  // nh
                    float val = acc[mt][nt][reg] + bv[row];
                    oVt[((size_t)bi * 1024 + row) * TT + tt] = (bf16)val;
                }
            }
        }
    }
}

// ---------------------------------------------------------------------------
// Output projection GEMM: 128x64 tile, 512 blocks (2/CU), BK=32, fp32 out.
// ---------------------------------------------------------------------------
__global__ __launch_bounds__(256)
void gemm_out(const bf16* __restrict__ A, const bf16* __restrict__ Bt,
              const float* __restrict__ bias, float* __restrict__ oF)
{
    __shared__ bf16 As[128 * 32];
    __shared__ bf16 Bs[64 * 32];

    const int t    = threadIdx.x;
    const int lane = t & 63;
    const int w    = t >> 6;
    const int quad = lane >> 4, l15 = lane & 15;
    const int m0   = blockIdx.y << 7;
    const int n0   = blockIdx.x << 6;
    const int wm   = (w >> 1) << 6;
    const int wn   = (w & 1)  << 5;

    const int jr0 = ((w * 2 + 0) << 4) + (lane >> 2);
    const int jr1 = ((w * 2 + 1) << 4) + (lane >> 2);
    const int jrB = (w << 4) + (lane >> 2);
    const int kch = (lane & 3) << 3;

    bf16* lA0 = As + (w * 2 + 0) * 512;
    bf16* lA1 = As + (w * 2 + 1) * 512;
    bf16* lB  = Bs + w * 512;

    const bf16* Ap0 = A  + (size_t)(m0 + jr0) * DD + kch;
    const bf16* Ap1 = A  + (size_t)(m0 + jr1) * DD + kch;
    const bf16* Bp  = Bt + (size_t)(n0 + jrB) * DD + kch;

    f32x4 acc[4][2] = {};

    for (int k0 = 0; k0 < DD; k0 += 32) {
        __syncthreads();
        gld16(Ap0 + k0, lA0);
        gld16(Ap1 + k0, lA1);
        gld16(Bp + k0, lB);
        __syncthreads();
        bf16x8 af[4], bfm[2];
        #pragma unroll
        for (int mt = 0; mt < 4; ++mt)
            af[mt] = *(const bf16x8*)(As + (wm + (mt << 4) + l15) * 32 + (quad << 3));
        #pragma unroll
        for (int nt = 0; nt < 2; ++nt)
            bfm[nt] = *(const bf16x8*)(Bs + (wn + (nt << 4) + l15) * 32 + (quad << 3));
        #pragma unroll
        for (int mt = 0; mt < 4; ++mt)
            #pragma unroll
            for (int nt = 0; nt < 2; ++nt)
                acc[mt][nt] = __builtin_amdgcn_mfma_f32_16x16x32_bf16(
                    af[mt], bfm[nt], acc[mt][nt], 0, 0, 0);
    }

    #pragma unroll
    for (int nt = 0; nt < 2; ++nt) {
        const int col = n0 + wn + (nt << 4) + l15;
        const float bcol = bias[col];
        #pragma unroll
        for (int mt = 0; mt < 4; ++mt) {
            #pragma unroll
            for (int reg = 0; reg < 4; ++reg) {
                const int row = m0 + wm + (mt << 4) + (quad << 2) + reg;
                oF[(size_t)row * DD + col] = acc[mt][nt][reg] + bcol;
            }
        }
    }
}

// ---------------------------------------------------------------------------
// MFMA flash attention v4: small blocks for occupancy.
// q-tile 64, 256 threads (4 waves); each wave owns 16 q rows over ALL k
// (no split-K merge). Grid 1024 blocks; LDS 24.5 KB -> up to 6 blocks/CU
// (vs 2 at R1), barriers span only 4 waves.
// V time-shares the K-lo LDS buffer: V global loads issued right after the
// K tile is staged (latency hides under QK MFMAs), written to LDS after the
// QK-consumption barrier (T14 issue-early/write-late).
// XOR-swizzled 16B chunks on write+read (T2), setprio (T5), defer-max (T13).
// __launch_bounds__(256,5): VGPR cap 102 — headroom over R1's 56, no spill.
// ---------------------------------------------------------------------------
__global__ __launch_bounds__(256, 5)
void attn_mfma(const bf16* __restrict__ Qh, const bf16* __restrict__ Ql,
               const bf16* __restrict__ Kh, const bf16* __restrict__ Kl,
               const bf16* __restrict__ Vt,
               const unsigned long long* __restrict__ mb64,
               bf16* __restrict__ AO)
{
    __shared__ bf16 KH[64 * 64];       // K-hi
    __shared__ bf16 KLV[64 * 64];      // K-lo, later V (time-shared)
    __shared__ bf16 PS[4][16 * 64];    // per-wave P, swizzled
    __shared__ unsigned long long MSK[64];

    const int t    = threadIdx.x;
    const int lane = t & 63;
    const int w    = t >> 6;           // 0..3
    const int quad = lane >> 4, l15 = lane & 15;
    const int bn   = blockIdx.y;
    const int b    = bn >> 4, n = bn & 15;
    const int q0   = blockIdx.x << 6;  // 64 q per block

    const bf16* Qbh = Qh + (size_t)bn * TT * HD;
    const bf16* Qbl = Ql + (size_t)bn * TT * HD;
    const bf16* Kbh = Kh + (size_t)bn * TT * HD;
    const bf16* Kbl = Kl + (size_t)bn * TT * HD;
    const bf16* Vtb = Vt + (size_t)bn * HD * TT;

    // Q fragments (B-operand: n=q=l15, k=h) — registers, loaded once
    const int qrow = q0 + (w << 4) + l15;
    bf16x8 qfh[2], qfl[2];
    qfh[0] = *(const bf16x8*)(Qbh + (size_t)qrow * HD + (quad << 3));
    qfh[1] = *(const bf16x8*)(Qbh + (size_t)qrow * HD + 32 + (quad << 3));
    qfl[0] = *(const bf16x8*)(Qbl + (size_t)qrow * HD + (quad << 3));
    qfl[1] = *(const bf16x8*)(Qbl + (size_t)qrow * HD + 32 + (quad << 3));

    f32x4 O[4];                         // O^T: row h=nt*16+quad*4+reg, col q=l15
    #pragma unroll
    for (int i = 0; i < 4; ++i) O[i] = (f32x4){0.f,0.f,0.f,0.f};
    float m_i = -INFINITY;
    float l_i = 0.f;

    // staging map: 256 threads cover 64 rows x 8 chunks, 2 chunks each
    const int rS  = t >> 2;                          // 0..63
    const int cp  = t & 3;                           // chunk pair
    const int cG0 = (cp * 2    ) << 3;
    const int cG1 = (cp * 2 + 1) << 3;
    const int cL0 = ((cp * 2    ) ^ (rS & 7)) << 3;  // swizzled LDS chunk
    const int cL1 = ((cp * 2 + 1) ^ (rS & 7)) << 3;
    // fragment-read swizzle key: row&7 == l15&7 for row = nt*16+l15
    const int sw8 = (l15 & 7) << 3;

    for (int it = 0; it < 32; ++it) {
        const int kb = it << 6;
        // prefetch K globals into regs
        const bf16* kr = Kbh + (size_t)(kb + rS) * HD;
        const bf16* lr = Kbl + (size_t)(kb + rS) * HD;
        bf16x8 kh0 = *(const bf16x8*)(kr + cG0);
        bf16x8 kh1 = *(const bf16x8*)(kr + cG1);
        bf16x8 kl0 = *(const bf16x8*)(lr + cG0);
        bf16x8 kl1 = *(const bf16x8*)(lr + cG1);
        unsigned long long mw = 0;
        if (t < 64)
            mw = mb64[((size_t)b * TT + q0 + t) * (TT / 64) + it];

        __syncthreads();   // B1: previous tile fully consumed
        *(bf16x8*)&KH [rS * 64 + cL0] = kh0;
        *(bf16x8*)&KH [rS * 64 + cL1] = kh1;
        *(bf16x8*)&KLV[rS * 64 + cL0] = kl0;
        *(bf16x8*)&KLV[rS * 64 + cL1] = kl1;
        if (t < 64) MSK[t] = mw;
        __syncthreads();   // B2: K tiles + mask visible

        // issue V loads now — latency hides under QK MFMAs (T14)
        const bf16* vr = Vtb + (size_t)rS * TT + kb;
        bf16x8 v0 = *(const bf16x8*)(vr + cG0);
        bf16x8 v1 = *(const bf16x8*)(vr + cG1);

        // S^T = K Q^T (rows s, cols q), split: Kh*Qh + Kl*Qh + Kh*Ql
        f32x4 s_acc[4];
        #pragma unroll
        for (int i = 0; i < 4; ++i) s_acc[i] = (f32x4){0.f,0.f,0.f,0.f};
        __builtin_amdgcn_s_setprio(1);
        #pragma unroll
        for (int k2 = 0; k2 < 2; ++k2) {
            #pragma unroll
            for (int nt = 0; nt < 4; ++nt) {
                const int ro = ((nt << 4) + l15) * 64;
                const int co = ((k2 << 5) + (quad << 3)) ^ sw8;
                bf16x8 bkh = *(const bf16x8*)&KH [ro + co];
                bf16x8 bkl = *(const bf16x8*)&KLV[ro + co];
                s_acc[nt] = __builtin_amdgcn_mfma_f32_16x16x32_bf16(bkh, qfh[k2], s_acc[nt], 0, 0, 0);
                s_acc[nt] = __builtin_amdgcn_mfma_f32_16x16x32_bf16(bkl, qfh[k2], s_acc[nt], 0, 0, 0);
                s_acc[nt] = __builtin_amdgcn_mfma_f32_16x16x32_bf16(bkh, qfl[k2], s_acc[nt], 0, 0, 0);
            }
        }
        __builtin_amdgcn_s_setprio(0);

        // per-lane softmax over s (16 local vals + cross-quad shuffles)
        const unsigned long long word = MSK[(w << 4) + l15];
        const unsigned w0 = (unsigned)word;
        const unsigned w1 = (unsigned)(word >> 32);
        float sv[16];
        #pragma unroll
        for (int nt = 0; nt < 4; ++nt) {
            const unsigned wrd = (nt & 2) ? w1 : w0;
            #pragma unroll
            for (int reg = 0; reg < 4; ++reg) {
                const int bit = ((nt & 1) << 4) + (quad << 2) + reg;
                sv[nt * 4 + reg] = ((wrd >> bit) & 1u) ? s_acc[nt][reg] : NEGINF_F;
            }
        }
        // tree max
        float a0 = fmaxf(sv[0], sv[1]),  a1 = fmaxf(sv[2], sv[3]);
        float a2 = fmaxf(sv[4], sv[5]),  a3 = fmaxf(sv[6], sv[7]);
        float a4 = fmaxf(sv[8], sv[9]),  a5 = fmaxf(sv[10], sv[11]);
        float a6 = fmaxf(sv[12], sv[13]), a7 = fmaxf(sv[14], sv[15]);
        float b0 = fmaxf(a0, a1), b1 = fmaxf(a2, a3);
        float b2 = fmaxf(a4, a5), b3 = fmaxf(a6, a7);
        float mx = fmaxf(fmaxf(b0, b1), fmaxf(b2, b3));
        mx = fmaxf(mx, __shfl_xor(mx, 16));
        mx = fmaxf(mx, __shfl_xor(mx, 32));

        // T13 defer-max (exp2 domain, THR=8)
        if (!__all(mx <= m_i + 8.0f)) {
            const float mnew  = fmaxf(m_i, mx);
            const float alpha = exp2f(m_i - mnew);   // exp2(-inf)=0 first tile
            l_i *= alpha;
            #pragma unroll
            for (int nt = 0; nt < 4; ++nt) {
                O[nt][0] *= alpha; O[nt][1] *= alpha;
                O[nt][2] *= alpha; O[nt][3] *= alpha;
            }
            m_i = mnew;
        }

        float p[16];
        #pragma unroll
        for (int i = 0; i < 16; ++i) p[i] = exp2f(sv[i] - m_i);
        float s0 = (p[0] + p[1]) + (p[2] + p[3]);
        float s1 = (p[4] + p[5]) + (p[6] + p[7]);
        float s2 = (p[8] + p[9]) + (p[10] + p[11]);
        float s3 = (p[12] + p[13]) + (p[14] + p[15]);
        float sum = (s0 + s1) + (s2 + s3);
        sum += __shfl_xor(sum, 16);
        sum += __shfl_xor(sum, 32);
        l_i += sum;

        #pragma unroll
        for (int nt = 0; nt < 4; ++nt) {
            bf16x4 pv = { (bf16)p[nt * 4 + 0], (bf16)p[nt * 4 + 1],
                          (bf16)p[nt * 4 + 2], (bf16)p[nt * 4 + 3] };
            *(bf16x4*)&PS[w][l15 * 64 + (((nt << 4) + (quad << 2)) ^ sw8)] = pv;
        }

        __syncthreads();   // B3: all QK reads of KLV done -> stage V over it
        *(bf16x8*)&KLV[rS * 64 + cL0] = v0;
        *(bf16x8*)&KLV[rS * 64 + cL1] = v1;
        __syncthreads();   // B4: V visible

        // O^T += Vt P^T  (A=Vt rows h, B=P rows q)
        __builtin_amdgcn_s_setprio(1);
        #pragma unroll
        for (int s2i = 0; s2i < 2; ++s2i) {
            bf16x8 ap = *(const bf16x8*)&PS[w][l15 * 64 + (((s2i << 5) + (quad << 3)) ^ sw8)];
            #pragma unroll
            for (int nt = 0; nt < 4; ++nt) {
                bf16x8 bv = *(const bf16x8*)&KLV[((nt << 4) + l15) * 64
                                                 + (((s2i << 5) + (quad << 3)) ^ sw8)];
                O[nt] = __builtin_amdgcn_mfma_f32_16x16x32_bf16(bv, ap, O[nt], 0, 0, 0);
            }
        }
        __builtin_amdgcn_s_setprio(0);
    }

    // normalize + write AO (bf16, [B*T][N*H]); lane owns col q, rows h
    {
        const float inv = 1.0f / l_i;
        const size_t base = ((size_t)b * TT + qrow) * (NHD * HD) + (size_t)n * HD;
        #pragma unroll
        for (int nt = 0; nt < 4; ++nt) {
            bf16x4 o = { (bf16)(O[nt][0] * inv), (bf16)(O[nt][1] * inv),
                         (bf16)(O[nt][2] * inv), (bf16)(O[nt][3] * inv) };
            *(bf16x4*)(AO + base + (nt << 4) + (quad << 2)) = o;
        }
    }
}

// ---------------------------------------------------------------------------
extern "C" void kernel_launch(void* const* d_in, const int* in_sizes, int n_in,
                              void* d_out, int out_size, void* d_ws, size_t ws_size,
                              hipStream_t stream)
{
    const float* X   = (const float*)d_in[0];
    const int*   msk = (const int*)d_in[1];
    const float* wq  = (const float*)d_in[2];
    const float* bq  = (const float*)d_in[3];
    const float* wk  = (const float*)d_in[4];
    const float* bk  = (const float*)d_in[5];
    const float* wv  = (const float*)d_in[6];
    const float* bv  = (const float*)d_in[7];
    const float* wo  = (const float*)d_in[8];
    const float* bo  = (const float*)d_in[9];
    const float* pds = (const float*)d_in[10];
    float* out = (float*)d_out;

    bf16* ws   = (bf16*)d_ws;
    bf16* Xh   = ws;                      // 4M  (later aliased by AO)
    bf16* Xl   = ws + 4194304;            // 4M
    bf16* WQKh = ws + 8388608;            // 2M  [2048 nh'][1024 d]
    bf16* WQKl = ws + 10485760;           // 2M
    bf16* Wvh  = ws + 12582912;           // 1M  [nh][d]
    bf16* Wob  = ws + 13631488;           // 1M  [d][nh]
    bf16* Qhb  = ws + 14680064;           // 4M  [b][n][t][h]
    bf16* Qlb  = ws + 18874368;
    bf16* Khb  = ws + 23068672;
    bf16* Klb  = ws + 27262976;
    unsigned char* mbits = (unsigned char*)(ws + 31457280);   // 1 MB
    bf16* Vtb  = ws + 32505856;           // 4M [b][nh][t]
    bf16* AOb  = Xh;                      // alias: Xh dead after proj

    dim3 blk(256);

    prep_all<<<12288, blk, 0, stream>>>(X, msk, wq, wk, wv, wo,
                                        Xh, Xl, WQKh, WQKl, Wvh, Wob, mbits);

    // fused QK + V projections
    gemm_proj<<<768, blk, 0, stream>>>(
        Xh, Xl, WQKh, WQKl, Wvh, bq, bk, bv, pds,
        Qhb, Qlb, Khb, Klb, Vtb);

    dim3 ga(TT / 64, BB * NHD);   // (32, 32) — q-tile 64, 4-wave blocks
    attn_mfma<<<ga, dim3(256), 0, stream>>>(
        Qhb, Qlb, Khb, Klb, Vtb, (const unsigned long long*)mbits, AOb);

    // output projection: M=4096, N=1024, K=1024, fp32 out, 128x64 tiles
    gemm_out<<<dim3(16, 32), blk, 0, stream>>>(AOb, Wob, bo, out);
}

// Round 4
// 310.477 us; speedup vs baseline: 1.6083x; 1.2447x over previous
//
#include <hip/hip_runtime.h>
#include <math.h>

typedef __bf16 bf16;
typedef __attribute__((ext_vector_type(8))) __bf16 bf16x8;
typedef __attribute__((ext_vector_type(4))) __bf16 bf16x4;
typedef __attribute__((ext_vector_type(4))) float f32x4;

#define BB 2
#define TT 2048
#define DD 1024
#define NHD 16
#define HD 64
#define MM (BB*TT)          // 4096
#define LOG2E_F 1.442695041f
#define NEGINF_F (-1.0e9f)

// async global->LDS, 16B per lane; LDS dest must be wave-uniform base
__device__ __forceinline__ void gld16(const bf16* g, bf16* l)
{
    __builtin_amdgcn_global_load_lds(
        (const __attribute__((address_space(1))) unsigned int*)g,
        (__attribute__((address_space(3))) unsigned int*)l, 16, 0, 0);
}

// ---------------------------------------------------------------------------
// fused prep: [0,4096) split_x; [4096,8192) weight transpose/convert;
// [8192,12288) mask -> ADDITIVE bf16 mask (0 or -1e9), written into d_out
// (16 MB, exactly out_size; dead until gemm_out overwrites it).
// ---------------------------------------------------------------------------
__global__ __launch_bounds__(256)
void prep_all(const float* __restrict__ X, const int* __restrict__ m,
              const float* __restrict__ wq, const float* __restrict__ wk,
              const float* __restrict__ wv, const float* __restrict__ wo,
              bf16* __restrict__ Xh, bf16* __restrict__ Xl,
              bf16* __restrict__ qkh, bf16* __restrict__ qkl,
              bf16* __restrict__ vh, bf16* __restrict__ ob,
              bf16* __restrict__ madd)
{
    __shared__ float tile[32][33];
    const int bid = blockIdx.x;
    const int t   = threadIdx.x;

    if (bid < 4096) {                         // split X -> hi/lo
        int i = bid * 256 + t;
        float4 v = ((const float4*)X)[i];
        float f[4] = {v.x, v.y, v.z, v.w};
        bf16x4 h, l;
        #pragma unroll
        for (int j = 0; j < 4; ++j) {
            bf16 hh = (bf16)f[j];
            h[j] = hh;
            l[j] = (bf16)(f[j] - (float)hh);
        }
        *(bf16x4*)(Xh + (size_t)i * 4) = h;
        *(bf16x4*)(Xl + (size_t)i * 4) = l;
        return;
    }
    if (bid < 8192) {                         // weights
        const int idx = bid - 4096;
        const int z   = idx >> 10;            // 0:wq 1:wk 2:wv 3:wo
        const int bx  = (idx & 31) << 5;      // nh block
        const int by  = ((idx >> 5) & 31) << 5;  // d block
        const int r   = t >> 3;
        const int c4  = (t & 7) << 2;
        if (z == 3) {
            float4 v = *(const float4*)(wo + (size_t)(by + r) * 1024 + bx + c4);
            bf16x4 o = { (bf16)v.x, (bf16)v.y, (bf16)v.z, (bf16)v.w };
            *(bf16x4*)(ob + (size_t)(by + r) * 1024 + bx + c4) = o;
            return;
        }
        const float* src = (z == 0) ? wq : ((z == 1) ? wk : wv);
        bf16* oh = (z == 0) ? qkh : ((z == 1) ? qkh + 1048576 : vh);
        bf16* ol = (z == 0) ? qkl : ((z == 1) ? qkl + 1048576 : nullptr);
        float4 v = *(const float4*)(src + (size_t)(by + r) * 1024 + bx + c4);
        tile[r][c4+0] = v.x; tile[r][c4+1] = v.y;
        tile[r][c4+2] = v.z; tile[r][c4+3] = v.w;
        __syncthreads();
        bf16x4 hv, lv;
        #pragma unroll
        for (int j = 0; j < 4; ++j) {
            float f = tile[c4 + j][r];
            bf16 h = (bf16)f;
            hv[j] = h;
            lv[j] = (bf16)(f - (float)h);
        }
        *(bf16x4*)(oh + (size_t)(bx + r) * 1024 + by + c4) = hv;
        if (ol)
            *(bf16x4*)(ol + (size_t)(bx + r) * 1024 + by + c4) = lv;
        return;
    }
    {                                         // mask -> additive bf16
        int i = (bid - 8192) * 256 + t;       // i < 1048576 (8 elems each)
        const int4* mp = (const int4*)m + (size_t)i * 2;
        int4 a  = mp[0];
        int4 b4 = mp[1];
        bf16x8 o;
        o[0] = (bf16)(a.x  ? 0.f : NEGINF_F);
        o[1] = (bf16)(a.y  ? 0.f : NEGINF_F);
        o[2] = (bf16)(a.z  ? 0.f : NEGINF_F);
        o[3] = (bf16)(a.w  ? 0.f : NEGINF_F);
        o[4] = (bf16)(b4.x ? 0.f : NEGINF_F);
        o[5] = (bf16)(b4.y ? 0.f : NEGINF_F);
        o[6] = (bf16)(b4.z ? 0.f : NEGINF_F);
        o[7] = (bf16)(b4.w ? 0.f : NEGINF_F);
        *(bf16x8*)(madd + (size_t)i * 8) = o;
    }
}

// ---------------------------------------------------------------------------
// Fused projection GEMM (768 blocks):
//  [0,512): QK — single K-sweep split (Xh*Wh + Xh*Wl + Xl*Wh), 128x128, BK=32;
//           col<1024 -> Q (scaled, exp2-domain), else K; split hi/lo out.
//  [512,768): V — C^T = Wvh · Xh^T, out Vt[b][nh][t] bf16 + bias.
// ---------------------------------------------------------------------------
__global__ __launch_bounds__(256)
void gemm_proj(const bf16* __restrict__ Xh, const bf16* __restrict__ Xl,
               const bf16* __restrict__ Wh, const bf16* __restrict__ Wl,
               const bf16* __restrict__ Wvh,
               const float* __restrict__ bq, const float* __restrict__ bk,
               const float* __restrict__ bv, const float* __restrict__ pds,
               bf16* __restrict__ oQh, bf16* __restrict__ oQl,
               bf16* __restrict__ oKh, bf16* __restrict__ oKl,
               bf16* __restrict__ oVt)
{
    __shared__ bf16 S[4][128 * 32];   // QK: Ah/Al/Bh/Bl ; V: uses S[0],S[2]

    const int bid  = blockIdx.x;
    const int t    = threadIdx.x;
    const int lane = t & 63;
    const int w    = t >> 6;
    const int quad = lane >> 4, l15 = lane & 15;
    const int wm   = (w >> 1) << 6;
    const int wn   = (w & 1)  << 6;

    const int jr0 = ((w * 2 + 0) << 4) + (lane >> 2);
    const int jr1 = ((w * 2 + 1) << 4) + (lane >> 2);
    const int kch = (lane & 3) << 3;
    const int off0 = (w * 2 + 0) * 512;
    const int off1 = (w * 2 + 1) * 512;

    if (bid < 512) {
        // ---------------- QK path ----------------
        const int m0 = (bid >> 4) << 7;
        const int n0 = (bid & 15) << 7;
        bf16* Ah = S[0]; bf16* Al = S[1]; bf16* Bh = S[2]; bf16* Bl = S[3];

        const bf16* pAh0 = Xh + (size_t)(m0 + jr0) * DD + kch;
        const bf16* pAh1 = Xh + (size_t)(m0 + jr1) * DD + kch;
        const bf16* pAl0 = Xl + (size_t)(m0 + jr0) * DD + kch;
        const bf16* pAl1 = Xl + (size_t)(m0 + jr1) * DD + kch;
        const bf16* pBh0 = Wh + (size_t)(n0 + jr0) * DD + kch;
        const bf16* pBh1 = Wh + (size_t)(n0 + jr1) * DD + kch;
        const bf16* pBl0 = Wl + (size_t)(n0 + jr0) * DD + kch;
        const bf16* pBl1 = Wl + (size_t)(n0 + jr1) * DD + kch;

        f32x4 acc[4][4] = {};

        for (int k0 = 0; k0 < DD; k0 += 32) {
            __syncthreads();
            gld16(pAh0 + k0, Ah + off0);  gld16(pAh1 + k0, Ah + off1);
            gld16(pAl0 + k0, Al + off0);  gld16(pAl1 + k0, Al + off1);
            gld16(pBh0 + k0, Bh + off0);  gld16(pBh1 + k0, Bh + off1);
            gld16(pBl0 + k0, Bl + off0);  gld16(pBl1 + k0, Bl + off1);
            __syncthreads();

            bf16x8 ah[4], bh[4];
            #pragma unroll
            for (int mt = 0; mt < 4; ++mt)
                ah[mt] = *(const bf16x8*)(Ah + (wm + (mt << 4) + l15) * 32 + (quad << 3));
            #pragma unroll
            for (int nt = 0; nt < 4; ++nt)
                bh[nt] = *(const bf16x8*)(Bh + (wn + (nt << 4) + l15) * 32 + (quad << 3));
            #pragma unroll
            for (int mt = 0; mt < 4; ++mt)
                #pragma unroll
                for (int nt = 0; nt < 4; ++nt)
                    acc[mt][nt] = __builtin_amdgcn_mfma_f32_16x16x32_bf16(
                        ah[mt], bh[nt], acc[mt][nt], 0, 0, 0);

            bf16x8 bl[4];
            #pragma unroll
            for (int nt = 0; nt < 4; ++nt)
                bl[nt] = *(const bf16x8*)(Bl + (wn + (nt << 4) + l15) * 32 + (quad << 3));
            #pragma unroll
            for (int mt = 0; mt < 4; ++mt)
                #pragma unroll
                for (int nt = 0; nt < 4; ++nt)
                    acc[mt][nt] = __builtin_amdgcn_mfma_f32_16x16x32_bf16(
                        ah[mt], bl[nt], acc[mt][nt], 0, 0, 0);

            bf16x8 al[4];
            #pragma unroll
            for (int mt = 0; mt < 4; ++mt)
                al[mt] = *(const bf16x8*)(Al + (wm + (mt << 4) + l15) * 32 + (quad << 3));
            #pragma unroll
            for (int mt = 0; mt < 4; ++mt)
                #pragma unroll
                for (int nt = 0; nt < 4; ++nt)
                    acc[mt][nt] = __builtin_amdgcn_mfma_f32_16x16x32_bf16(
                        al[mt], bh[nt], acc[mt][nt], 0, 0, 0);
        }

        #pragma unroll
        for (int nt = 0; nt < 4; ++nt) {
            const int col = n0 + wn + (nt << 4) + l15;
            const int isQ = (col < 1024);
            const int nh  = col & 1023;
            const int n   = nh >> 6, h = nh & 63;
            const float bcol = isQ ? bq[nh] : bk[nh];
            float s = 1.f;
            if (isQ) {
                float x  = pds[h];
                float sp = fmaxf(x, 0.f) + log1pf(expf(-fabsf(x)));  // softplus
                s = (LOG2E_F * LOG2E_F / 8.0f) * sp;  // exp2 domain
            }
            bf16* dH = isQ ? oQh : oKh;
            bf16* dL = isQ ? oQl : oKl;
            #pragma unroll
            for (int mt = 0; mt < 4; ++mt) {
                #pragma unroll
                for (int reg = 0; reg < 4; ++reg) {
                    const int row = m0 + wm + (mt << 4) + (quad << 2) + reg;
                    const int bi  = row >> 11;
                    const int tt  = row & (TT - 1);
                    float val = (acc[mt][nt][reg] + bcol) * s;
                    const size_t idx = (((size_t)bi * NHD + n) * TT + tt) * HD + h;
                    bf16 hi = (bf16)val;
                    dH[idx] = hi;
                    dL[idx] = (bf16)(val - (float)hi);
                }
            }
        }
    } else {
        // ---------------- V path ----------------
        const int idx = bid - 512;
        const int m0  = (idx >> 5) << 7;      // nh tile (8)
        const int n0  = (idx & 31) << 7;      // bt tile (32)
        bf16* As = S[0]; bf16* Bs = S[2];

        const bf16* Ap0 = Wvh + (size_t)(m0 + jr0) * DD + kch;
        const bf16* Ap1 = Wvh + (size_t)(m0 + jr1) * DD + kch;
        const bf16* Bp0 = Xh  + (size_t)(n0 + jr0) * DD + kch;
        const bf16* Bp1 = Xh  + (size_t)(n0 + jr1) * DD + kch;

        f32x4 acc[4][4] = {};

        for (int k0 = 0; k0 < DD; k0 += 32) {
            __syncthreads();
            gld16(Ap0 + k0, As + off0);
            gld16(Ap1 + k0, As + off1);
            gld16(Bp0 + k0, Bs + off0);
            gld16(Bp1 + k0, Bs + off1);
            __syncthreads();
            bf16x8 af[4], bfm[4];
            #pragma unroll
            for (int mt = 0; mt < 4; ++mt)
                af[mt] = *(const bf16x8*)(As + (wm + (mt << 4) + l15) * 32 + (quad << 3));
            #pragma unroll
            for (int nt = 0; nt < 4; ++nt)
                bfm[nt] = *(const bf16x8*)(Bs + (wn + (nt << 4) + l15) * 32 + (quad << 3));
            #pragma unroll
            for (int mt = 0; mt < 4; ++mt)
                #pragma unroll
                for (int nt = 0; nt < 4; ++nt)
                    acc[mt][nt] = __builtin_amdgcn_mfma_f32_16x16x32_bf16(
                        af[mt], bfm[nt], acc[mt][nt], 0, 0, 0);
        }

        #pragma unroll
        for (int nt = 0; nt < 4; ++nt) {
            const int col = n0 + wn + (nt << 4) + l15;   // bt
            const int bi  = col >> 11;
            const int tt  = col & (TT - 1);
            #pragma unroll
            for (int mt = 0; mt < 4; ++mt) {
                #pragma unroll
                for (int reg = 0; reg < 4; ++reg) {
                    const int row = m0 + wm + (mt << 4) + (quad << 2) + reg;  // nh
                    float val = acc[mt][nt][reg] + bv[row];
                    oVt[((size_t)bi * 1024 + row) * TT + tt] = (bf16)val;
                }
            }
        }
    }
}

// ---------------------------------------------------------------------------
// Output projection GEMM: 128x64 tile, 512 blocks (2/CU), BK=32, fp32 out.
// ---------------------------------------------------------------------------
__global__ __launch_bounds__(256)
void gemm_out(const bf16* __restrict__ A, const bf16* __restrict__ Bt,
              const float* __restrict__ bias, float* __restrict__ oF)
{
    __shared__ bf16 As[128 * 32];
    __shared__ bf16 Bs[64 * 32];

    const int t    = threadIdx.x;
    const int lane = t & 63;
    const int w    = t >> 6;
    const int quad = lane >> 4, l15 = lane & 15;
    const int m0   = blockIdx.y << 7;
    const int n0   = blockIdx.x << 6;
    const int wm   = (w >> 1) << 6;
    const int wn   = (w & 1)  << 5;

    const int jr0 = ((w * 2 + 0) << 4) + (lane >> 2);
    const int jr1 = ((w * 2 + 1) << 4) + (lane >> 2);
    const int jrB = (w << 4) + (lane >> 2);
    const int kch = (lane & 3) << 3;

    bf16* lA0 = As + (w * 2 + 0) * 512;
    bf16* lA1 = As + (w * 2 + 1) * 512;
    bf16* lB  = Bs + w * 512;

    const bf16* Ap0 = A  + (size_t)(m0 + jr0) * DD + kch;
    const bf16* Ap1 = A  + (size_t)(m0 + jr1) * DD + kch;
    const bf16* Bp  = Bt + (size_t)(n0 + jrB) * DD + kch;

    f32x4 acc[4][2] = {};

    for (int k0 = 0; k0 < DD; k0 += 32) {
        __syncthreads();
        gld16(Ap0 + k0, lA0);
        gld16(Ap1 + k0, lA1);
        gld16(Bp + k0, lB);
        __syncthreads();
        bf16x8 af[4], bfm[2];
        #pragma unroll
        for (int mt = 0; mt < 4; ++mt)
            af[mt] = *(const bf16x8*)(As + (wm + (mt << 4) + l15) * 32 + (quad << 3));
        #pragma unroll
        for (int nt = 0; nt < 2; ++nt)
            bfm[nt] = *(const bf16x8*)(Bs + (wn + (nt << 4) + l15) * 32 + (quad << 3));
        #pragma unroll
        for (int mt = 0; mt < 4; ++mt)
            #pragma unroll
            for (int nt = 0; nt < 2; ++nt)
                acc[mt][nt] = __builtin_amdgcn_mfma_f32_16x16x32_bf16(
                    af[mt], bfm[nt], acc[mt][nt], 0, 0, 0);
    }

    #pragma unroll
    for (int nt = 0; nt < 2; ++nt) {
        const int col = n0 + wn + (nt << 4) + l15;
        const float bcol = bias[col];
        #pragma unroll
        for (int mt = 0; mt < 4; ++mt) {
            #pragma unroll
            for (int reg = 0; reg < 4; ++reg) {
                const int row = m0 + wm + (mt << 4) + (quad << 2) + reg;
                oF[(size_t)row * DD + col] = acc[mt][nt][reg] + bcol;
            }
        }
    }
}

// ---------------------------------------------------------------------------
// MFMA flash attention (R1 structure: 512 thr, q-tile 128, 8 waves) with the
// mask FOLDED INTO THE MFMA ACCUMULATOR: s_acc is initialized from a staged
// additive bf16 mask tile (0 / -1e9), so the softmax needs NO per-element
// bit-extract/cndmask (~40 VALU/lane/iter removed). Online-softmax rescale
// (alpha=exp2(m_old-m_new)=0) provably wipes any all-masked-prefix state.
// XOR-swizzled 16B chunks on write+read (T2), setprio (T5), defer-max (T13).
// ---------------------------------------------------------------------------
__global__ __launch_bounds__(512)
void attn_mfma(const bf16* __restrict__ Qh, const bf16* __restrict__ Ql,
               const bf16* __restrict__ Kh, const bf16* __restrict__ Kl,
               const bf16* __restrict__ Vt,
               const bf16* __restrict__ Madd,
               bf16* __restrict__ AO)
{
    __shared__ bf16 Ksh[64 * 64];
    __shared__ bf16 Ksl[64 * 64];
    __shared__ bf16 Vts[64 * 64];      // [h][s], swizzled
    __shared__ bf16 MT [128 * 64];     // additive mask [q][s], swizzled
    __shared__ bf16 PS [8][16 * 64];   // per-wave P, swizzled

    const int t    = threadIdx.x;
    const int lane = t & 63;
    const int w    = t >> 6;           // 0..7
    const int quad = lane >> 4, l15 = lane & 15;
    const int bn   = blockIdx.y;
    const int b    = bn >> 4, n = bn & 15;
    const int q0   = blockIdx.x << 7;  // 128 q per block

    const bf16* Qbh = Qh + (size_t)bn * TT * HD;
    const bf16* Qbl = Ql + (size_t)bn * TT * HD;
    const bf16* Kbh = Kh + (size_t)bn * TT * HD;
    const bf16* Kbl = Kl + (size_t)bn * TT * HD;
    const bf16* Vtb = Vt + (size_t)bn * HD * TT;
    const bf16* Mb  = Madd + (size_t)b * TT * TT;

    // Q fragments (B-operand: n=q=l15, k=h) — registers, loaded once
    const int qrow = q0 + (w << 4) + l15;
    bf16x8 qfh[2], qfl[2];
    qfh[0] = *(const bf16x8*)(Qbh + (size_t)qrow * HD + (quad << 3));
    qfh[1] = *(const bf16x8*)(Qbh + (size_t)qrow * HD + 32 + (quad << 3));
    qfl[0] = *(const bf16x8*)(Qbl + (size_t)qrow * HD + (quad << 3));
    qfl[1] = *(const bf16x8*)(Qbl + (size_t)qrow * HD + 32 + (quad << 3));

    f32x4 O[4];                         // O^T: row h=nt*16+quad*4+reg, col q=l15
    #pragma unroll
    for (int i = 0; i < 4; ++i) O[i] = (f32x4){0.f,0.f,0.f,0.f};
    float m_i = -INFINITY;
    float l_i = 0.f;

    // staging map: lane handles row rS, GLOBAL chunk (t&7); LDS write chunk
    // is XOR-swizzled so each 8-lane group fills one full 128B row.
    const int rS = t >> 3;                          // 0..63
    const int cG = (t & 7) << 3;                    // global elem offset
    const int cL = (((t & 7) ^ (rS & 7)) << 3);     // swizzled LDS offset
    // fragment-read swizzle key: row&7 == l15&7
    const int sw8 = (l15 & 7) << 3;
    // q row this wave's lane reads in MT
    const int qtr = (w << 4) + l15;                 // 0..127

    for (int kb = 0; kb < TT; kb += 64) {
        // prefetch globals into regs
        bf16x8 khv = *(const bf16x8*)(Kbh + (size_t)(kb + rS) * HD + cG);
        bf16x8 klv = *(const bf16x8*)(Kbl + (size_t)(kb + rS) * HD + cG);
        bf16x8 vv  = *(const bf16x8*)(Vtb + (size_t)rS * TT + kb + cG);
        const bf16* mrow = Mb + (size_t)(q0 + rS) * TT + kb;
        bf16x8 m0v = *(const bf16x8*)(mrow + cG);
        bf16x8 m1v = *(const bf16x8*)(mrow + (size_t)64 * TT + cG);

        __syncthreads();   // B1: previous tile fully consumed
        *(bf16x8*)&Ksh[rS * 64 + cL] = khv;
        *(bf16x8*)&Ksl[rS * 64 + cL] = klv;
        *(bf16x8*)&Vts[rS * 64 + cL] = vv;
        *(bf16x8*)&MT [rS * 64 + cL]        = m0v;
        *(bf16x8*)&MT [(64 + rS) * 64 + cL] = m1v;
        __syncthreads();   // B2: tiles visible

        // s_acc init = additive mask (C-in of the MFMA). Lane needs
        // M[q=qtr][s = nt*16 + quad*4 .. +3]: chunk (nt*2 + quad/2) ^ swz,
        // +8B when quad odd. 2-way bank conflict max (free).
        f32x4 s_acc[4];
        #pragma unroll
        for (int nt = 0; nt < 4; ++nt) {
            const int moff = ((((nt << 1) + (quad >> 1)) ^ (l15 & 7)) << 3)
                             + ((quad & 1) << 2);
            ushort4 mu = *(const ushort4*)&MT[qtr * 64 + moff];
            s_acc[nt][0] = __uint_as_float((unsigned)mu.x << 16);
            s_acc[nt][1] = __uint_as_float((unsigned)mu.y << 16);
            s_acc[nt][2] = __uint_as_float((unsigned)mu.z << 16);
            s_acc[nt][3] = __uint_as_float((unsigned)mu.w << 16);
        }

        // S^T = K Q^T + M (rows s, cols q), split: Kh*Qh + Kl*Qh + Kh*Ql
        __builtin_amdgcn_s_setprio(1);
        #pragma unroll
        for (int k2 = 0; k2 < 2; ++k2) {
            #pragma unroll
            for (int nt = 0; nt < 4; ++nt) {
                const int ro = ((nt << 4) + l15) * 64;
                const int co = ((k2 << 5) + (quad << 3)) ^ sw8;
                bf16x8 bkh = *(const bf16x8*)&Ksh[ro + co];
                bf16x8 bkl = *(const bf16x8*)&Ksl[ro + co];
                s_acc[nt] = __builtin_amdgcn_mfma_f32_16x16x32_bf16(bkh, qfh[k2], s_acc[nt], 0, 0, 0);
                s_acc[nt] = __builtin_amdgcn_mfma_f32_16x16x32_bf16(bkl, qfh[k2], s_acc[nt], 0, 0, 0);
                s_acc[nt] = __builtin_amdgcn_mfma_f32_16x16x32_bf16(bkh, qfl[k2], s_acc[nt], 0, 0, 0);
            }
        }
        __builtin_amdgcn_s_setprio(0);

        // per-lane softmax over s — mask already inside s_acc.
        // 3-ary max groupings (v_max3 fusion): 7 ops instead of 15.
        float t0 = fmaxf(fmaxf(s_acc[0][0], s_acc[0][1]), s_acc[0][2]);
        float t1 = fmaxf(fmaxf(s_acc[0][3], s_acc[1][0]), s_acc[1][1]);
        float t2 = fmaxf(fmaxf(s_acc[1][2], s_acc[1][3]), s_acc[2][0]);
        float t3 = fmaxf(fmaxf(s_acc[2][1], s_acc[2][2]), s_acc[2][3]);
        float t4 = fmaxf(fmaxf(s_acc[3][0], s_acc[3][1]), s_acc[3][2]);
        float mx = fmaxf(fmaxf(fmaxf(t0, t1), t2),
                         fmaxf(fmaxf(t3, t4), s_acc[3][3]));
        mx = fmaxf(mx, __shfl_xor(mx, 16));
        mx = fmaxf(mx, __shfl_xor(mx, 32));

        // T13 defer-max (exp2 domain, THR=8)
        if (!__all(mx <= m_i + 8.0f)) {
            const float mnew  = fmaxf(m_i, mx);
            const float alpha = exp2f(m_i - mnew);   // exp2(-inf)=0 first tile
            l_i *= alpha;
            #pragma unroll
            for (int nt = 0; nt < 4; ++nt) {
                O[nt][0] *= alpha; O[nt][1] *= alpha;
                O[nt][2] *= alpha; O[nt][3] *= alpha;
            }
            m_i = mnew;
        }

        float p[16];
        #pragma unroll
        for (int nt = 0; nt < 4; ++nt)
            #pragma unroll
            for (int reg = 0; reg < 4; ++reg)
                p[nt * 4 + reg] = exp2f(s_acc[nt][reg] - m_i);  // masked -> 0
        float s0 = (p[0] + p[1]) + (p[2] + p[3]);
        float s1 = (p[4] + p[5]) + (p[6] + p[7]);
        float s2 = (p[8] + p[9]) + (p[10] + p[11]);
        float s3 = (p[12] + p[13]) + (p[14] + p[15]);
        float sum = (s0 + s1) + (s2 + s3);
        sum += __shfl_xor(sum, 16);
        sum += __shfl_xor(sum, 32);
        l_i += sum;

        #pragma unroll
        for (int nt = 0; nt < 4; ++nt) {
            bf16x4 pv = { (bf16)p[nt * 4 + 0], (bf16)p[nt * 4 + 1],
                          (bf16)p[nt * 4 + 2], (bf16)p[nt * 4 + 3] };
            *(bf16x4*)&PS[w][l15 * 64 + (((nt << 4) + (quad << 2)) ^ sw8)] = pv;
        }

        // O^T += Vt P^T  (A=Vt rows h, B=P rows q)
        __builtin_amdgcn_s_setprio(1);
        #pragma unroll
        for (int s2i = 0; s2i < 2; ++s2i) {
            bf16x8 ap = *(const bf16x8*)&PS[w][l15 * 64 + (((s2i << 5) + (quad << 3)) ^ sw8)];
            #pragma unroll
            for (int nt = 0; nt < 4; ++nt) {
                bf16x8 bv = *(const bf16x8*)&Vts[((nt << 4) + l15) * 64
                                                 + (((s2i << 5) + (quad << 3)) ^ sw8)];
                O[nt] = __builtin_amdgcn_mfma_f32_16x16x32_bf16(bv, ap, O[nt], 0, 0, 0);
            }
        }
        __builtin_amdgcn_s_setprio(0);
    }

    // normalize + write AO (bf16, [B*T][N*H]); lane owns col q, rows h
    {
        const float inv = 1.0f / l_i;
        const size_t base = ((size_t)b * TT + qrow) * (NHD * HD) + (size_t)n * HD;
        #pragma unroll
        for (int nt = 0; nt < 4; ++nt) {
            bf16x4 o = { (bf16)(O[nt][0] * inv), (bf16)(O[nt][1] * inv),
                         (bf16)(O[nt][2] * inv), (bf16)(O[nt][3] * inv) };
            *(bf16x4*)(AO + base + (nt << 4) + (quad << 2)) = o;
        }
    }
}

// ---------------------------------------------------------------------------
extern "C" void kernel_launch(void* const* d_in, const int* in_sizes, int n_in,
                              void* d_out, int out_size, void* d_ws, size_t ws_size,
                              hipStream_t stream)
{
    const float* X   = (const float*)d_in[0];
    const int*   msk = (const int*)d_in[1];
    const float* wq  = (const float*)d_in[2];
    const float* bq  = (const float*)d_in[3];
    const float* wk  = (const float*)d_in[4];
    const float* bk  = (const float*)d_in[5];
    const float* wv  = (const float*)d_in[6];
    const float* bv  = (const float*)d_in[7];
    const float* wo  = (const float*)d_in[8];
    const float* bo  = (const float*)d_in[9];
    const float* pds = (const float*)d_in[10];
    float* out = (float*)d_out;

    bf16* ws   = (bf16*)d_ws;
    bf16* Xh   = ws;                      // 4M  (later aliased by AO)
    bf16* Xl   = ws + 4194304;            // 4M
    bf16* WQKh = ws + 8388608;            // 2M  [2048 nh'][1024 d]
    bf16* WQKl = ws + 10485760;           // 2M
    bf16* Wvh  = ws + 12582912;           // 1M  [nh][d]
    bf16* Wob  = ws + 13631488;           // 1M  [d][nh]
    bf16* Qhb  = ws + 14680064;           // 4M  [b][n][t][h]
    bf16* Qlb  = ws + 18874368;
    bf16* Khb  = ws + 23068672;
    bf16* Klb  = ws + 27262976;
    bf16* Vtb  = ws + 32505856;           // 4M [b][nh][t]
    bf16* AOb  = Xh;                      // alias: Xh dead after proj
    // additive mask lives in d_out (16 MB = out_size exactly); it is consumed
    // by attn_mfma BEFORE gemm_out overwrites d_out with the final result.
    bf16* madd = (bf16*)d_out;

    dim3 blk(256);

    prep_all<<<12288, blk, 0, stream>>>(X, msk, wq, wk, wv, wo,
                                        Xh, Xl, WQKh, WQKl, Wvh, Wob, madd);

    // fused QK + V projections
    gemm_proj<<<768, blk, 0, stream>>>(
        Xh, Xl, WQKh, WQKl, Wvh, bq, bk, bv, pds,
        Qhb, Qlb, Khb, Klb, Vtb);

    dim3 ga(TT / 128, BB * NHD);   // (16, 32)
    attn_mfma<<<ga, dim3(512), 0, stream>>>(
        Qhb, Qlb, Khb, Klb, Vtb, madd, AOb);

    // output projection: M=4096, N=1024, K=1024, fp32 out, 128x64 tiles
    gemm_out<<<dim3(16, 32), blk, 0, stream>>>(AOb, Wob, bo, out);
}

// Round 5
// 305.671 us; speedup vs baseline: 1.6335x; 1.0157x over previous
//
#include <hip/hip_runtime.h>
#include <math.h>

typedef __bf16 bf16;
typedef __attribute__((ext_vector_type(8))) __bf16 bf16x8;
typedef __attribute__((ext_vector_type(4))) __bf16 bf16x4;
typedef __attribute__((ext_vector_type(4))) float f32x4;

#define BB 2
#define TT 2048
#define DD 1024
#define NHD 16
#define HD 64
#define MM (BB*TT)          // 4096
#define LOG2E_F 1.442695041f
#define NEGINF_F (-1.0e9f)

// async global->LDS, 16B per lane; LDS dest must be wave-uniform base
__device__ __forceinline__ void gld16(const bf16* g, bf16* l)
{
    __builtin_amdgcn_global_load_lds(
        (const __attribute__((address_space(1))) unsigned int*)g,
        (__attribute__((address_space(3))) unsigned int*)l, 16, 0, 0);
}

// ---------------------------------------------------------------------------
// fused prep: [0,4096) split_x; [4096,8192) weight transpose/convert;
// [8192,12288) mask -> ADDITIVE bf16 mask (0 or -1e9), written into d_out
// (16 MB, exactly out_size; dead until gemm_out overwrites it).
// ---------------------------------------------------------------------------
__global__ __launch_bounds__(256)
void prep_all(const float* __restrict__ X, const int* __restrict__ m,
              const float* __restrict__ wq, const float* __restrict__ wk,
              const float* __restrict__ wv, const float* __restrict__ wo,
              bf16* __restrict__ Xh, bf16* __restrict__ Xl,
              bf16* __restrict__ qkh, bf16* __restrict__ qkl,
              bf16* __restrict__ vh, bf16* __restrict__ ob,
              bf16* __restrict__ madd)
{
    __shared__ float tile[32][33];
    const int bid = blockIdx.x;
    const int t   = threadIdx.x;

    if (bid < 4096) {                         // split X -> hi/lo
        int i = bid * 256 + t;
        float4 v = ((const float4*)X)[i];
        float f[4] = {v.x, v.y, v.z, v.w};
        bf16x4 h, l;
        #pragma unroll
        for (int j = 0; j < 4; ++j) {
            bf16 hh = (bf16)f[j];
            h[j] = hh;
            l[j] = (bf16)(f[j] - (float)hh);
        }
        *(bf16x4*)(Xh + (size_t)i * 4) = h;
        *(bf16x4*)(Xl + (size_t)i * 4) = l;
        return;
    }
    if (bid < 8192) {                         // weights
        const int idx = bid - 4096;
        const int z   = idx >> 10;            // 0:wq 1:wk 2:wv 3:wo
        const int bx  = (idx & 31) << 5;      // nh block
        const int by  = ((idx >> 5) & 31) << 5;  // d block
        const int r   = t >> 3;
        const int c4  = (t & 7) << 2;
        if (z == 3) {
            float4 v = *(const float4*)(wo + (size_t)(by + r) * 1024 + bx + c4);
            bf16x4 o = { (bf16)v.x, (bf16)v.y, (bf16)v.z, (bf16)v.w };
            *(bf16x4*)(ob + (size_t)(by + r) * 1024 + bx + c4) = o;
            return;
        }
        const float* src = (z == 0) ? wq : ((z == 1) ? wk : wv);
        bf16* oh = (z == 0) ? qkh : ((z == 1) ? qkh + 1048576 : vh);
        bf16* ol = (z == 0) ? qkl : ((z == 1) ? qkl + 1048576 : nullptr);
        float4 v = *(const float4*)(src + (size_t)(by + r) * 1024 + bx + c4);
        tile[r][c4+0] = v.x; tile[r][c4+1] = v.y;
        tile[r][c4+2] = v.z; tile[r][c4+3] = v.w;
        __syncthreads();
        bf16x4 hv, lv;
        #pragma unroll
        for (int j = 0; j < 4; ++j) {
            float f = tile[c4 + j][r];
            bf16 h = (bf16)f;
            hv[j] = h;
            lv[j] = (bf16)(f - (float)h);
        }
        *(bf16x4*)(oh + (size_t)(bx + r) * 1024 + by + c4) = hv;
        if (ol)
            *(bf16x4*)(ol + (size_t)(bx + r) * 1024 + by + c4) = lv;
        return;
    }
    {                                         // mask -> additive bf16
        int i = (bid - 8192) * 256 + t;       // i < 1048576 (8 elems each)
        const int4* mp = (const int4*)m + (size_t)i * 2;
        int4 a  = mp[0];
        int4 b4 = mp[1];
        bf16x8 o;
        o[0] = (bf16)(a.x  ? 0.f : NEGINF_F);
        o[1] = (bf16)(a.y  ? 0.f : NEGINF_F);
        o[2] = (bf16)(a.z  ? 0.f : NEGINF_F);
        o[3] = (bf16)(a.w  ? 0.f : NEGINF_F);
        o[4] = (bf16)(b4.x ? 0.f : NEGINF_F);
        o[5] = (bf16)(b4.y ? 0.f : NEGINF_F);
        o[6] = (bf16)(b4.z ? 0.f : NEGINF_F);
        o[7] = (bf16)(b4.w ? 0.f : NEGINF_F);
        *(bf16x8*)(madd + (size_t)i * 8) = o;
    }
}

// ---------------------------------------------------------------------------
// Fused projection GEMM (768 blocks), XCD-swizzled (T1):
//  [0,512): QK — single K-sweep split (Xh*Wh + Xh*Wl + Xl*Wh), 128x128, BK=32;
//           col<1024 -> Q (scaled, exp2-domain), else K; split hi/lo out.
//  [512,768): V — C^T = Wvh · Xh^T, out Vt[b][nh][t] bf16 + bias.
// ---------------------------------------------------------------------------
__global__ __launch_bounds__(256)
void gemm_proj(const bf16* __restrict__ Xh, const bf16* __restrict__ Xl,
               const bf16* __restrict__ Wh, const bf16* __restrict__ Wl,
               const bf16* __restrict__ Wvh,
               const float* __restrict__ bq, const float* __restrict__ bk,
               const float* __restrict__ bv, const float* __restrict__ pds,
               bf16* __restrict__ oQh, bf16* __restrict__ oQl,
               bf16* __restrict__ oKh, bf16* __restrict__ oKl,
               bf16* __restrict__ oVt)
{
    __shared__ bf16 S[4][128 * 32];   // QK: Ah/Al/Bh/Bl ; V: uses S[0],S[2]

    int bid = blockIdx.x;
    // bijective XCD swizzle within each segment (8 XCDs): contiguous tile
    // chunks per XCD -> A/B panel reuse lands in one L2.
    if (bid < 512) bid = ((bid & 7) << 6) + (bid >> 3);
    else {
        int idx = bid - 512;
        bid = 512 + (((idx & 7) << 5) + (idx >> 3));
    }

    const int t    = threadIdx.x;
    const int lane = t & 63;
    const int w    = t >> 6;
    const int quad = lane >> 4, l15 = lane & 15;
    const int wm   = (w >> 1) << 6;
    const int wn   = (w & 1)  << 6;

    const int jr0 = ((w * 2 + 0) << 4) + (lane >> 2);
    const int jr1 = ((w * 2 + 1) << 4) + (lane >> 2);
    const int kch = (lane & 3) << 3;
    const int off0 = (w * 2 + 0) * 512;
    const int off1 = (w * 2 + 1) * 512;

    if (bid < 512) {
        // ---------------- QK path ----------------
        const int m0 = (bid >> 4) << 7;
        const int n0 = (bid & 15) << 7;
        bf16* Ah = S[0]; bf16* Al = S[1]; bf16* Bh = S[2]; bf16* Bl = S[3];

        const bf16* pAh0 = Xh + (size_t)(m0 + jr0) * DD + kch;
        const bf16* pAh1 = Xh + (size_t)(m0 + jr1) * DD + kch;
        const bf16* pAl0 = Xl + (size_t)(m0 + jr0) * DD + kch;
        const bf16* pAl1 = Xl + (size_t)(m0 + jr1) * DD + kch;
        const bf16* pBh0 = Wh + (size_t)(n0 + jr0) * DD + kch;
        const bf16* pBh1 = Wh + (size_t)(n0 + jr1) * DD + kch;
        const bf16* pBl0 = Wl + (size_t)(n0 + jr0) * DD + kch;
        const bf16* pBl1 = Wl + (size_t)(n0 + jr1) * DD + kch;

        f32x4 acc[4][4] = {};

        for (int k0 = 0; k0 < DD; k0 += 32) {
            __syncthreads();
            gld16(pAh0 + k0, Ah + off0);  gld16(pAh1 + k0, Ah + off1);
            gld16(pAl0 + k0, Al + off0);  gld16(pAl1 + k0, Al + off1);
            gld16(pBh0 + k0, Bh + off0);  gld16(pBh1 + k0, Bh + off1);
            gld16(pBl0 + k0, Bl + off0);  gld16(pBl1 + k0, Bl + off1);
            __syncthreads();

            bf16x8 ah[4], bh[4];
            #pragma unroll
            for (int mt = 0; mt < 4; ++mt)
                ah[mt] = *(const bf16x8*)(Ah + (wm + (mt << 4) + l15) * 32 + (quad << 3));
            #pragma unroll
            for (int nt = 0; nt < 4; ++nt)
                bh[nt] = *(const bf16x8*)(Bh + (wn + (nt << 4) + l15) * 32 + (quad << 3));
            #pragma unroll
            for (int mt = 0; mt < 4; ++mt)
                #pragma unroll
                for (int nt = 0; nt < 4; ++nt)
                    acc[mt][nt] = __builtin_amdgcn_mfma_f32_16x16x32_bf16(
                        ah[mt], bh[nt], acc[mt][nt], 0, 0, 0);

            bf16x8 bl[4];
            #pragma unroll
            for (int nt = 0; nt < 4; ++nt)
                bl[nt] = *(const bf16x8*)(Bl + (wn + (nt << 4) + l15) * 32 + (quad << 3));
            #pragma unroll
            for (int mt = 0; mt < 4; ++mt)
                #pragma unroll
                for (int nt = 0; nt < 4; ++nt)
                    acc[mt][nt] = __builtin_amdgcn_mfma_f32_16x16x32_bf16(
                        ah[mt], bl[nt], acc[mt][nt], 0, 0, 0);

            bf16x8 al[4];
            #pragma unroll
            for (int mt = 0; mt < 4; ++mt)
                al[mt] = *(const bf16x8*)(Al + (wm + (mt << 4) + l15) * 32 + (quad << 3));
            #pragma unroll
            for (int mt = 0; mt < 4; ++mt)
                #pragma unroll
                for (int nt = 0; nt < 4; ++nt)
                    acc[mt][nt] = __builtin_amdgcn_mfma_f32_16x16x32_bf16(
                        al[mt], bh[nt], acc[mt][nt], 0, 0, 0);
        }

        #pragma unroll
        for (int nt = 0; nt < 4; ++nt) {
            const int col = n0 + wn + (nt << 4) + l15;
            const int isQ = (col < 1024);
            const int nh  = col & 1023;
            const int n   = nh >> 6, h = nh & 63;
            const float bcol = isQ ? bq[nh] : bk[nh];
            float s = 1.f;
            if (isQ) {
                float x  = pds[h];
                float sp = fmaxf(x, 0.f) + log1pf(expf(-fabsf(x)));  // softplus
                s = (LOG2E_F * LOG2E_F / 8.0f) * sp;  // exp2 domain
            }
            bf16* dH = isQ ? oQh : oKh;
            bf16* dL = isQ ? oQl : oKl;
            #pragma unroll
            for (int mt = 0; mt < 4; ++mt) {
                #pragma unroll
                for (int reg = 0; reg < 4; ++reg) {
                    const int row = m0 + wm + (mt << 4) + (quad << 2) + reg;
                    const int bi  = row >> 11;
                    const int tt  = row & (TT - 1);
                    float val = (acc[mt][nt][reg] + bcol) * s;
                    const size_t idx = (((size_t)bi * NHD + n) * TT + tt) * HD + h;
                    bf16 hi = (bf16)val;
                    dH[idx] = hi;
                    dL[idx] = (bf16)(val - (float)hi);
                }
            }
        }
    } else {
        // ---------------- V path ----------------
        const int idx = bid - 512;
        const int m0  = (idx >> 5) << 7;      // nh tile (8)
        const int n0  = (idx & 31) << 7;      // bt tile (32)
        bf16* As = S[0]; bf16* Bs = S[2];

        const bf16* Ap0 = Wvh + (size_t)(m0 + jr0) * DD + kch;
        const bf16* Ap1 = Wvh + (size_t)(m0 + jr1) * DD + kch;
        const bf16* Bp0 = Xh  + (size_t)(n0 + jr0) * DD + kch;
        const bf16* Bp1 = Xh  + (size_t)(n0 + jr1) * DD + kch;

        f32x4 acc[4][4] = {};

        for (int k0 = 0; k0 < DD; k0 += 32) {
            __syncthreads();
            gld16(Ap0 + k0, As + off0);
            gld16(Ap1 + k0, As + off1);
            gld16(Bp0 + k0, Bs + off0);
            gld16(Bp1 + k0, Bs + off1);
            __syncthreads();
            bf16x8 af[4], bfm[4];
            #pragma unroll
            for (int mt = 0; mt < 4; ++mt)
                af[mt] = *(const bf16x8*)(As + (wm + (mt << 4) + l15) * 32 + (quad << 3));
            #pragma unroll
            for (int nt = 0; nt < 4; ++nt)
                bfm[nt] = *(const bf16x8*)(Bs + (wn + (nt << 4) + l15) * 32 + (quad << 3));
            #pragma unroll
            for (int mt = 0; mt < 4; ++mt)
                #pragma unroll
                for (int nt = 0; nt < 4; ++nt)
                    acc[mt][nt] = __builtin_amdgcn_mfma_f32_16x16x32_bf16(
                        af[mt], bfm[nt], acc[mt][nt], 0, 0, 0);
        }

        #pragma unroll
        for (int nt = 0; nt < 4; ++nt) {
            const int col = n0 + wn + (nt << 4) + l15;   // bt
            const int bi  = col >> 11;
            const int tt  = col & (TT - 1);
            #pragma unroll
            for (int mt = 0; mt < 4; ++mt) {
                #pragma unroll
                for (int reg = 0; reg < 4; ++reg) {
                    const int row = m0 + wm + (mt << 4) + (quad << 2) + reg;  // nh
                    float val = acc[mt][nt][reg] + bv[row];
                    oVt[((size_t)bi * 1024 + row) * TT + tt] = (bf16)val;
                }
            }
        }
    }
}

// ---------------------------------------------------------------------------
// Output projection GEMM: 128x64 tile, 512 blocks (2/CU), BK=32, fp32 out.
// ---------------------------------------------------------------------------
__global__ __launch_bounds__(256)
void gemm_out(const bf16* __restrict__ A, const bf16* __restrict__ Bt,
              const float* __restrict__ bias, float* __restrict__ oF)
{
    __shared__ bf16 As[128 * 32];
    __shared__ bf16 Bs[64 * 32];

    const int t    = threadIdx.x;
    const int lane = t & 63;
    const int w    = t >> 6;
    const int quad = lane >> 4, l15 = lane & 15;
    const int m0   = blockIdx.y << 7;
    const int n0   = blockIdx.x << 6;
    const int wm   = (w >> 1) << 6;
    const int wn   = (w & 1)  << 5;

    const int jr0 = ((w * 2 + 0) << 4) + (lane >> 2);
    const int jr1 = ((w * 2 + 1) << 4) + (lane >> 2);
    const int jrB = (w << 4) + (lane >> 2);
    const int kch = (lane & 3) << 3;

    bf16* lA0 = As + (w * 2 + 0) * 512;
    bf16* lA1 = As + (w * 2 + 1) * 512;
    bf16* lB  = Bs + w * 512;

    const bf16* Ap0 = A  + (size_t)(m0 + jr0) * DD + kch;
    const bf16* Ap1 = A  + (size_t)(m0 + jr1) * DD + kch;
    const bf16* Bp  = Bt + (size_t)(n0 + jrB) * DD + kch;

    f32x4 acc[4][2] = {};

    for (int k0 = 0; k0 < DD; k0 += 32) {
        __syncthreads();
        gld16(Ap0 + k0, lA0);
        gld16(Ap1 + k0, lA1);
        gld16(Bp + k0, lB);
        __syncthreads();
        bf16x8 af[4], bfm[2];
        #pragma unroll
        for (int mt = 0; mt < 4; ++mt)
            af[mt] = *(const bf16x8*)(As + (wm + (mt << 4) + l15) * 32 + (quad << 3));
        #pragma unroll
        for (int nt = 0; nt < 2; ++nt)
            bfm[nt] = *(const bf16x8*)(Bs + (wn + (nt << 4) + l15) * 32 + (quad << 3));
        #pragma unroll
        for (int mt = 0; mt < 4; ++mt)
            #pragma unroll
            for (int nt = 0; nt < 2; ++nt)
                acc[mt][nt] = __builtin_amdgcn_mfma_f32_16x16x32_bf16(
                    af[mt], bfm[nt], acc[mt][nt], 0, 0, 0);
    }

    #pragma unroll
    for (int nt = 0; nt < 2; ++nt) {
        const int col = n0 + wn + (nt << 4) + l15;
        const float bcol = bias[col];
        #pragma unroll
        for (int mt = 0; mt < 4; ++mt) {
            #pragma unroll
            for (int reg = 0; reg < 4; ++reg) {
                const int row = m0 + wm + (mt << 4) + (quad << 2) + reg;
                oF[(size_t)row * DD + col] = acc[mt][nt][reg] + bcol;
            }
        }
    }
}

// ---------------------------------------------------------------------------
// MFMA flash attention (512 thr, q-tile 128, 8 waves).
// Mask folded into the MFMA accumulator via LANE-DIRECT global ushort4 loads
// (no MT LDS tile; mask is L3-hot, loads issued at iter top, consumed after
// B2). Row-sum folded into the MATRIX pipe: an extra MFMA per s2i with an
// all-ones A fragment accumulates Ol = sum_s p[s][q] alongside O, with the
// identical alpha rescale -> no per-iter sum tree / shuffles / l_i updates.
// XOR-swizzled 16B chunks on write+read (T2), setprio (T5), defer-max (T13).
// ---------------------------------------------------------------------------
__global__ __launch_bounds__(512)
void attn_mfma(const bf16* __restrict__ Qh, const bf16* __restrict__ Ql,
               const bf16* __restrict__ Kh, const bf16* __restrict__ Kl,
               const bf16* __restrict__ Vt,
               const bf16* __restrict__ Madd,
               bf16* __restrict__ AO)
{
    __shared__ bf16 Ksh[64 * 64];
    __shared__ bf16 Ksl[64 * 64];
    __shared__ bf16 Vts[64 * 64];      // [h][s], swizzled
    __shared__ bf16 PS [8][16 * 64];   // per-wave P, swizzled

    const int t    = threadIdx.x;
    const int lane = t & 63;
    const int w    = t >> 6;           // 0..7
    const int quad = lane >> 4, l15 = lane & 15;
    const int bn   = blockIdx.y;
    const int b    = bn >> 4, n = bn & 15;
    const int q0   = blockIdx.x << 7;  // 128 q per block

    const bf16* Qbh = Qh + (size_t)bn * TT * HD;
    const bf16* Qbl = Ql + (size_t)bn * TT * HD;
    const bf16* Kbh = Kh + (size_t)bn * TT * HD;
    const bf16* Kbl = Kl + (size_t)bn * TT * HD;
    const bf16* Vtb = Vt + (size_t)bn * HD * TT;
    const bf16* Mb  = Madd + (size_t)b * TT * TT;

    // Q fragments (B-operand: n=q=l15, k=h) — registers, loaded once
    const int qrow = q0 + (w << 4) + l15;
    bf16x8 qfh[2], qfl[2];
    qfh[0] = *(const bf16x8*)(Qbh + (size_t)qrow * HD + (quad << 3));
    qfh[1] = *(const bf16x8*)(Qbh + (size_t)qrow * HD + 32 + (quad << 3));
    qfl[0] = *(const bf16x8*)(Qbl + (size_t)qrow * HD + (quad << 3));
    qfl[1] = *(const bf16x8*)(Qbl + (size_t)qrow * HD + 32 + (quad << 3));

    f32x4 O[4];                         // O^T: row h=nt*16+quad*4+reg, col q=l15
    #pragma unroll
    for (int i = 0; i < 4; ++i) O[i] = (f32x4){0.f,0.f,0.f,0.f};
    f32x4 Ol = (f32x4){0.f,0.f,0.f,0.f};   // row-sum accumulator (ones-row)
    float m_i = -INFINITY;

    const bf16 onev = (bf16)1.0f;
    const bf16x8 ones = { onev, onev, onev, onev, onev, onev, onev, onev };

    // staging map: lane handles row rS, GLOBAL chunk (t&7); LDS write chunk
    // is XOR-swizzled so each 8-lane group fills one full 128B row.
    const int rS = t >> 3;                          // 0..63
    const int cG = (t & 7) << 3;                    // global elem offset
    const int cL = (((t & 7) ^ (rS & 7)) << 3);     // swizzled LDS offset
    // fragment-read swizzle key: row&7 == l15&7
    const int sw8 = (l15 & 7) << 3;

    // lane-direct mask base: this lane's q row, quad's 4-elem group
    const bf16* mrow0 = Mb + (size_t)qrow * TT + (quad << 2);

    for (int kb = 0; kb < TT; kb += 64) {
        // prefetch globals into regs
        bf16x8 khv = *(const bf16x8*)(Kbh + (size_t)(kb + rS) * HD + cG);
        bf16x8 klv = *(const bf16x8*)(Kbl + (size_t)(kb + rS) * HD + cG);
        bf16x8 vv  = *(const bf16x8*)(Vtb + (size_t)rS * TT + kb + cG);
        // lane-direct mask quads (s = nt*16 + quad*4 + reg), consumed post-B2
        const bf16* mr = mrow0 + kb;
        ushort4 mu0 = *(const ushort4*)(mr);
        ushort4 mu1 = *(const ushort4*)(mr + 16);
        ushort4 mu2 = *(const ushort4*)(mr + 32);
        ushort4 mu3 = *(const ushort4*)(mr + 48);

        __syncthreads();   // B1: previous tile fully consumed
        *(bf16x8*)&Ksh[rS * 64 + cL] = khv;
        *(bf16x8*)&Ksl[rS * 64 + cL] = klv;
        *(bf16x8*)&Vts[rS * 64 + cL] = vv;
        __syncthreads();   // B2: tiles visible

        // s_acc init = additive mask (C-in of the MFMA)
        f32x4 s_acc[4];
        s_acc[0][0] = __uint_as_float((unsigned)mu0.x << 16);
        s_acc[0][1] = __uint_as_float((unsigned)mu0.y << 16);
        s_acc[0][2] = __uint_as_float((unsigned)mu0.z << 16);
        s_acc[0][3] = __uint_as_float((unsigned)mu0.w << 16);
        s_acc[1][0] = __uint_as_float((unsigned)mu1.x << 16);
        s_acc[1][1] = __uint_as_float((unsigned)mu1.y << 16);
        s_acc[1][2] = __uint_as_float((unsigned)mu1.z << 16);
        s_acc[1][3] = __uint_as_float((unsigned)mu1.w << 16);
        s_acc[2][0] = __uint_as_float((unsigned)mu2.x << 16);
        s_acc[2][1] = __uint_as_float((unsigned)mu2.y << 16);
        s_acc[2][2] = __uint_as_float((unsigned)mu2.z << 16);
        s_acc[2][3] = __uint_as_float((unsigned)mu2.w << 16);
        s_acc[3][0] = __uint_as_float((unsigned)mu3.x << 16);
        s_acc[3][1] = __uint_as_float((unsigned)mu3.y << 16);
        s_acc[3][2] = __uint_as_float((unsigned)mu3.z << 16);
        s_acc[3][3] = __uint_as_float((unsigned)mu3.w << 16);

        // S^T = K Q^T + M (rows s, cols q), split: Kh*Qh + Kl*Qh + Kh*Ql
        __builtin_amdgcn_s_setprio(1);
        #pragma unroll
        for (int k2 = 0; k2 < 2; ++k2) {
            #pragma unroll
            for (int nt = 0; nt < 4; ++nt) {
                const int ro = ((nt << 4) + l15) * 64;
                const int co = ((k2 << 5) + (quad << 3)) ^ sw8;
                bf16x8 bkh = *(const bf16x8*)&Ksh[ro + co];
                bf16x8 bkl = *(const bf16x8*)&Ksl[ro + co];
                s_acc[nt] = __builtin_amdgcn_mfma_f32_16x16x32_bf16(bkh, qfh[k2], s_acc[nt], 0, 0, 0);
                s_acc[nt] = __builtin_amdgcn_mfma_f32_16x16x32_bf16(bkl, qfh[k2], s_acc[nt], 0, 0, 0);
                s_acc[nt] = __builtin_amdgcn_mfma_f32_16x16x32_bf16(bkh, qfl[k2], s_acc[nt], 0, 0, 0);
            }
        }
        __builtin_amdgcn_s_setprio(0);

        // per-lane softmax over s — mask already inside s_acc.
        // 3-ary max groupings (v_max3 fusion): ~7 ops instead of 15.
        float t0 = fmaxf(fmaxf(s_acc[0][0], s_acc[0][1]), s_acc[0][2]);
        float t1 = fmaxf(fmaxf(s_acc[0][3], s_acc[1][0]), s_acc[1][1]);
        float t2 = fmaxf(fmaxf(s_acc[1][2], s_acc[1][3]), s_acc[2][0]);
        float t3 = fmaxf(fmaxf(s_acc[2][1], s_acc[2][2]), s_acc[2][3]);
        float t4 = fmaxf(fmaxf(s_acc[3][0], s_acc[3][1]), s_acc[3][2]);
        float mx = fmaxf(fmaxf(fmaxf(t0, t1), t2),
                         fmaxf(fmaxf(t3, t4), s_acc[3][3]));
        mx = fmaxf(mx, __shfl_xor(mx, 16));
        mx = fmaxf(mx, __shfl_xor(mx, 32));

        // T13 defer-max (exp2 domain, THR=8); Ol rescales with O
        if (!__all(mx <= m_i + 8.0f)) {
            const float mnew  = fmaxf(m_i, mx);
            const float alpha = exp2f(m_i - mnew);   // exp2(-inf)=0 first tile
            #pragma unroll
            for (int nt = 0; nt < 4; ++nt) {
                O[nt][0] *= alpha; O[nt][1] *= alpha;
                O[nt][2] *= alpha; O[nt][3] *= alpha;
            }
            Ol[0] *= alpha; Ol[1] *= alpha; Ol[2] *= alpha; Ol[3] *= alpha;
            m_i = mnew;
        }

        float p[16];
        #pragma unroll
        for (int nt = 0; nt < 4; ++nt)
            #pragma unroll
            for (int reg = 0; reg < 4; ++reg)
                p[nt * 4 + reg] = exp2f(s_acc[nt][reg] - m_i);  // masked -> 0

        #pragma unroll
        for (int nt = 0; nt < 4; ++nt) {
            bf16x4 pv = { (bf16)p[nt * 4 + 0], (bf16)p[nt * 4 + 1],
                          (bf16)p[nt * 4 + 2], (bf16)p[nt * 4 + 3] };
            *(bf16x4*)&PS[w][l15 * 64 + (((nt << 4) + (quad << 2)) ^ sw8)] = pv;
        }

        // O^T += Vt P^T  (A=Vt rows h, B=P rows q); ones-row MFMA -> row sums
        __builtin_amdgcn_s_setprio(1);
        #pragma unroll
        for (int s2i = 0; s2i < 2; ++s2i) {
            bf16x8 ap = *(const bf16x8*)&PS[w][l15 * 64 + (((s2i << 5) + (quad << 3)) ^ sw8)];
            Ol = __builtin_amdgcn_mfma_f32_16x16x32_bf16(ones, ap, Ol, 0, 0, 0);
            #pragma unroll
            for (int nt = 0; nt < 4; ++nt) {
                bf16x8 bv = *(const bf16x8*)&Vts[((nt << 4) + l15) * 64
                                                 + (((s2i << 5) + (quad << 3)) ^ sw8)];
                O[nt] = __builtin_amdgcn_mfma_f32_16x16x32_bf16(bv, ap, O[nt], 0, 0, 0);
            }
        }
        __builtin_amdgcn_s_setprio(0);
    }

    // normalize + write AO (bf16, [B*T][N*H]); lane owns col q, rows h.
    // Ol regs all equal Σ_s p[s][q=l15] — every lane holds its own l.
    {
        const float inv = 1.0f / Ol[0];
        const size_t base = ((size_t)b * TT + qrow) * (NHD * HD) + (size_t)n * HD;
        #pragma unroll
        for (int nt = 0; nt < 4; ++nt) {
            bf16x4 o = { (bf16)(O[nt][0] * inv), (bf16)(O[nt][1] * inv),
                         (bf16)(O[nt][2] * inv), (bf16)(O[nt][3] * inv) };
            *(bf16x4*)(AO + base + (nt << 4) + (quad << 2)) = o;
        }
    }
}

// ---------------------------------------------------------------------------
extern "C" void kernel_launch(void* const* d_in, const int* in_sizes, int n_in,
                              void* d_out, int out_size, void* d_ws, size_t ws_size,
                              hipStream_t stream)
{
    const float* X   = (const float*)d_in[0];
    const int*   msk = (const int*)d_in[1];
    const float* wq  = (const float*)d_in[2];
    const float* bq  = (const float*)d_in[3];
    const float* wk  = (const float*)d_in[4];
    const float* bk  = (const float*)d_in[5];
    const float* wv  = (const float*)d_in[6];
    const float* bv  = (const float*)d_in[7];
    const float* wo  = (const float*)d_in[8];
    const float* bo  = (const float*)d_in[9];
    const float* pds = (const float*)d_in[10];
    float* out = (float*)d_out;

    bf16* ws   = (bf16*)d_ws;
    bf16* Xh   = ws;                      // 4M  (later aliased by AO)
    bf16* Xl   = ws + 4194304;            // 4M
    bf16* WQKh = ws + 8388608;            // 2M  [2048 nh'][1024 d]
    bf16* WQKl = ws + 10485760;           // 2M
    bf16* Wvh  = ws + 12582912;           // 1M  [nh][d]
    bf16* Wob  = ws + 13631488;           // 1M  [d][nh]
    bf16* Qhb  = ws + 14680064;           // 4M  [b][n][t][h]
    bf16* Qlb  = ws + 18874368;
    bf16* Khb  = ws + 23068672;
    bf16* Klb  = ws + 27262976;
    bf16* Vtb  = ws + 32505856;           // 4M [b][nh][t]
    bf16* AOb  = Xh;                      // alias: Xh dead after proj
    // additive mask lives in d_out (16 MB = out_size exactly); it is consumed
    // by attn_mfma BEFORE gemm_out overwrites d_out with the final result.
    bf16* madd = (bf16*)d_out;

    dim3 blk(256);

    prep_all<<<12288, blk, 0, stream>>>(X, msk, wq, wk, wv, wo,
                                        Xh, Xl, WQKh, WQKl, Wvh, Wob, madd);

    // fused QK + V projections
    gemm_proj<<<768, blk, 0, stream>>>(
        Xh, Xl, WQKh, WQKl, Wvh, bq, bk, bv, pds,
        Qhb, Qlb, Khb, Klb, Vtb);

    dim3 ga(TT / 128, BB * NHD);   // (16, 32)
    attn_mfma<<<ga, dim3(512), 0, stream>>>(
        Qhb, Qlb, Khb, Klb, Vtb, madd, AOb);

    // output projection: M=4096, N=1024, K=1024, fp32 out, 128x64 tiles
    gemm_out<<<dim3(16, 32), blk, 0, stream>>>(AOb, Wob, bo, out);
}

// Round 6
// 304.776 us; speedup vs baseline: 1.6383x; 1.0029x over previous
//
#include <hip/hip_runtime.h>
#include <math.h>

typedef __bf16 bf16;
typedef __attribute__((ext_vector_type(8))) __bf16 bf16x8;
typedef __attribute__((ext_vector_type(4))) __bf16 bf16x4;
typedef __attribute__((ext_vector_type(4))) float f32x4;

#define BB 2
#define TT 2048
#define DD 1024
#define NHD 16
#define HD 64
#define MM (BB*TT)          // 4096
#define LOG2E_F 1.442695041f
#define NEGINF_F (-1.0e9f)

// async global->LDS, 16B per lane; LDS dest must be wave-uniform base
__device__ __forceinline__ void gld16(const bf16* g, bf16* l)
{
    __builtin_amdgcn_global_load_lds(
        (const __attribute__((address_space(1))) unsigned int*)g,
        (__attribute__((address_space(3))) unsigned int*)l, 16, 0, 0);
}

// ---------------------------------------------------------------------------
// fused prep: [0,4096) split_x; [4096,8192) weight transpose/convert;
// [8192,12288) mask -> ADDITIVE bf16 mask (0 or -1e9), written into d_out
// (16 MB, exactly out_size; dead until gemm_out overwrites it).
// ---------------------------------------------------------------------------
__global__ __launch_bounds__(256)
void prep_all(const float* __restrict__ X, const int* __restrict__ m,
              const float* __restrict__ wq, const float* __restrict__ wk,
              const float* __restrict__ wv, const float* __restrict__ wo,
              bf16* __restrict__ Xh, bf16* __restrict__ Xl,
              bf16* __restrict__ qkh, bf16* __restrict__ qkl,
              bf16* __restrict__ vh, bf16* __restrict__ ob,
              bf16* __restrict__ madd)
{
    __shared__ float tile[32][33];
    const int bid = blockIdx.x;
    const int t   = threadIdx.x;

    if (bid < 4096) {                         // split X -> hi/lo
        int i = bid * 256 + t;
        float4 v = ((const float4*)X)[i];
        float f[4] = {v.x, v.y, v.z, v.w};
        bf16x4 h, l;
        #pragma unroll
        for (int j = 0; j < 4; ++j) {
            bf16 hh = (bf16)f[j];
            h[j] = hh;
            l[j] = (bf16)(f[j] - (float)hh);
        }
        *(bf16x4*)(Xh + (size_t)i * 4) = h;
        *(bf16x4*)(Xl + (size_t)i * 4) = l;
        return;
    }
    if (bid < 8192) {                         // weights
        const int idx = bid - 4096;
        const int z   = idx >> 10;            // 0:wq 1:wk 2:wv 3:wo
        const int bx  = (idx & 31) << 5;      // nh block
        const int by  = ((idx >> 5) & 31) << 5;  // d block
        const int r   = t >> 3;
        const int c4  = (t & 7) << 2;
        if (z == 3) {
            float4 v = *(const float4*)(wo + (size_t)(by + r) * 1024 + bx + c4);
            bf16x4 o = { (bf16)v.x, (bf16)v.y, (bf16)v.z, (bf16)v.w };
            *(bf16x4*)(ob + (size_t)(by + r) * 1024 + bx + c4) = o;
            return;
        }
        const float* src = (z == 0) ? wq : ((z == 1) ? wk : wv);
        bf16* oh = (z == 0) ? qkh : ((z == 1) ? qkh + 1048576 : vh);
        bf16* ol = (z == 0) ? qkl : ((z == 1) ? qkl + 1048576 : nullptr);
        float4 v = *(const float4*)(src + (size_t)(by + r) * 1024 + bx + c4);
        tile[r][c4+0] = v.x; tile[r][c4+1] = v.y;
        tile[r][c4+2] = v.z; tile[r][c4+3] = v.w;
        __syncthreads();
        bf16x4 hv, lv;
        #pragma unroll
        for (int j = 0; j < 4; ++j) {
            float f = tile[c4 + j][r];
            bf16 h = (bf16)f;
            hv[j] = h;
            lv[j] = (bf16)(f - (float)h);
        }
        *(bf16x4*)(oh + (size_t)(bx + r) * 1024 + by + c4) = hv;
        if (ol)
            *(bf16x4*)(ol + (size_t)(bx + r) * 1024 + by + c4) = lv;
        return;
    }
    {                                         // mask -> additive bf16
        int i = (bid - 8192) * 256 + t;       // i < 1048576 (8 elems each)
        const int4* mp = (const int4*)m + (size_t)i * 2;
        int4 a  = mp[0];
        int4 b4 = mp[1];
        bf16x8 o;
        o[0] = (bf16)(a.x  ? 0.f : NEGINF_F);
        o[1] = (bf16)(a.y  ? 0.f : NEGINF_F);
        o[2] = (bf16)(a.z  ? 0.f : NEGINF_F);
        o[3] = (bf16)(a.w  ? 0.f : NEGINF_F);
        o[4] = (bf16)(b4.x ? 0.f : NEGINF_F);
        o[5] = (bf16)(b4.y ? 0.f : NEGINF_F);
        o[6] = (bf16)(b4.z ? 0.f : NEGINF_F);
        o[7] = (bf16)(b4.w ? 0.f : NEGINF_F);
        *(bf16x8*)(madd + (size_t)i * 8) = o;
    }
}

// ---------------------------------------------------------------------------
// Fused projection GEMM (768 blocks), XCD-swizzled (T1):
//  [0,512): QK — single K-sweep split (Xh*Wh + Xh*Wl + Xl*Wh), 128x128, BK=32;
//           col<1024 -> Q (scaled, exp2-domain), else K; split hi/lo out.
//  [512,768): V — C^T = Wvh · Xh^T, out Vt[b][nh][t] bf16 + bias.
// ---------------------------------------------------------------------------
__global__ __launch_bounds__(256)
void gemm_proj(const bf16* __restrict__ Xh, const bf16* __restrict__ Xl,
               const bf16* __restrict__ Wh, const bf16* __restrict__ Wl,
               const bf16* __restrict__ Wvh,
               const float* __restrict__ bq, const float* __restrict__ bk,
               const float* __restrict__ bv, const float* __restrict__ pds,
               bf16* __restrict__ oQh, bf16* __restrict__ oQl,
               bf16* __restrict__ oKh, bf16* __restrict__ oKl,
               bf16* __restrict__ oVt)
{
    __shared__ bf16 S[4][128 * 32];   // QK: Ah/Al/Bh/Bl ; V: uses S[0],S[2]

    int bid = blockIdx.x;
    // bijective XCD swizzle within each segment (8 XCDs): contiguous tile
    // chunks per XCD -> A/B panel reuse lands in one L2.
    if (bid < 512) bid = ((bid & 7) << 6) + (bid >> 3);
    else {
        int idx = bid - 512;
        bid = 512 + (((idx & 7) << 5) + (idx >> 3));
    }

    const int t    = threadIdx.x;
    const int lane = t & 63;
    const int w    = t >> 6;
    const int quad = lane >> 4, l15 = lane & 15;
    const int wm   = (w >> 1) << 6;
    const int wn   = (w & 1)  << 6;

    const int jr0 = ((w * 2 + 0) << 4) + (lane >> 2);
    const int jr1 = ((w * 2 + 1) << 4) + (lane >> 2);
    const int kch = (lane & 3) << 3;
    const int off0 = (w * 2 + 0) * 512;
    const int off1 = (w * 2 + 1) * 512;

    if (bid < 512) {
        // ---------------- QK path ----------------
        const int m0 = (bid >> 4) << 7;
        const int n0 = (bid & 15) << 7;
        bf16* Ah = S[0]; bf16* Al = S[1]; bf16* Bh = S[2]; bf16* Bl = S[3];

        const bf16* pAh0 = Xh + (size_t)(m0 + jr0) * DD + kch;
        const bf16* pAh1 = Xh + (size_t)(m0 + jr1) * DD + kch;
        const bf16* pAl0 = Xl + (size_t)(m0 + jr0) * DD + kch;
        const bf16* pAl1 = Xl + (size_t)(m0 + jr1) * DD + kch;
        const bf16* pBh0 = Wh + (size_t)(n0 + jr0) * DD + kch;
        const bf16* pBh1 = Wh + (size_t)(n0 + jr1) * DD + kch;
        const bf16* pBl0 = Wl + (size_t)(n0 + jr0) * DD + kch;
        const bf16* pBl1 = Wl + (size_t)(n0 + jr1) * DD + kch;

        f32x4 acc[4][4] = {};

        for (int k0 = 0; k0 < DD; k0 += 32) {
            __syncthreads();
            gld16(pAh0 + k0, Ah + off0);  gld16(pAh1 + k0, Ah + off1);
            gld16(pAl0 + k0, Al + off0);  gld16(pAl1 + k0, Al + off1);
            gld16(pBh0 + k0, Bh + off0);  gld16(pBh1 + k0, Bh + off1);
            gld16(pBl0 + k0, Bl + off0);  gld16(pBl1 + k0, Bl + off1);
            __syncthreads();

            bf16x8 ah[4], bh[4];
            #pragma unroll
            for (int mt = 0; mt < 4; ++mt)
                ah[mt] = *(const bf16x8*)(Ah + (wm + (mt << 4) + l15) * 32 + (quad << 3));
            #pragma unroll
            for (int nt = 0; nt < 4; ++nt)
                bh[nt] = *(const bf16x8*)(Bh + (wn + (nt << 4) + l15) * 32 + (quad << 3));
            #pragma unroll
            for (int mt = 0; mt < 4; ++mt)
                #pragma unroll
                for (int nt = 0; nt < 4; ++nt)
                    acc[mt][nt] = __builtin_amdgcn_mfma_f32_16x16x32_bf16(
                        ah[mt], bh[nt], acc[mt][nt], 0, 0, 0);

            bf16x8 bl[4];
            #pragma unroll
            for (int nt = 0; nt < 4; ++nt)
                bl[nt] = *(const bf16x8*)(Bl + (wn + (nt << 4) + l15) * 32 + (quad << 3));
            #pragma unroll
            for (int mt = 0; mt < 4; ++mt)
                #pragma unroll
                for (int nt = 0; nt < 4; ++nt)
                    acc[mt][nt] = __builtin_amdgcn_mfma_f32_16x16x32_bf16(
                        ah[mt], bl[nt], acc[mt][nt], 0, 0, 0);

            bf16x8 al[4];
            #pragma unroll
            for (int mt = 0; mt < 4; ++mt)
                al[mt] = *(const bf16x8*)(Al + (wm + (mt << 4) + l15) * 32 + (quad << 3));
            #pragma unroll
            for (int mt = 0; mt < 4; ++mt)
                #pragma unroll
                for (int nt = 0; nt < 4; ++nt)
                    acc[mt][nt] = __builtin_amdgcn_mfma_f32_16x16x32_bf16(
                        al[mt], bh[nt], acc[mt][nt], 0, 0, 0);
        }

        #pragma unroll
        for (int nt = 0; nt < 4; ++nt) {
            const int col = n0 + wn + (nt << 4) + l15;
            const int isQ = (col < 1024);
            const int nh  = col & 1023;
            const int n   = nh >> 6, h = nh & 63;
            const float bcol = isQ ? bq[nh] : bk[nh];
            float s = 1.f;
            if (isQ) {
                float x  = pds[h];
                float sp = fmaxf(x, 0.f) + log1pf(expf(-fabsf(x)));  // softplus
                s = (LOG2E_F * LOG2E_F / 8.0f) * sp;  // exp2 domain
            }
            bf16* dH = isQ ? oQh : oKh;
            bf16* dL = isQ ? oQl : oKl;
            #pragma unroll
            for (int mt = 0; mt < 4; ++mt) {
                #pragma unroll
                for (int reg = 0; reg < 4; ++reg) {
                    const int row = m0 + wm + (mt << 4) + (quad << 2) + reg;
                    const int bi  = row >> 11;
                    const int tt  = row & (TT - 1);
                    float val = (acc[mt][nt][reg] + bcol) * s;
                    const size_t idx = (((size_t)bi * NHD + n) * TT + tt) * HD + h;
                    bf16 hi = (bf16)val;
                    dH[idx] = hi;
                    dL[idx] = (bf16)(val - (float)hi);
                }
            }
        }
    } else {
        // ---------------- V path ----------------
        const int idx = bid - 512;
        const int m0  = (idx >> 5) << 7;      // nh tile (8)
        const int n0  = (idx & 31) << 7;      // bt tile (32)
        bf16* As = S[0]; bf16* Bs = S[2];

        const bf16* Ap0 = Wvh + (size_t)(m0 + jr0) * DD + kch;
        const bf16* Ap1 = Wvh + (size_t)(m0 + jr1) * DD + kch;
        const bf16* Bp0 = Xh  + (size_t)(n0 + jr0) * DD + kch;
        const bf16* Bp1 = Xh  + (size_t)(n0 + jr1) * DD + kch;

        f32x4 acc[4][4] = {};

        for (int k0 = 0; k0 < DD; k0 += 32) {
            __syncthreads();
            gld16(Ap0 + k0, As + off0);
            gld16(Ap1 + k0, As + off1);
            gld16(Bp0 + k0, Bs + off0);
            gld16(Bp1 + k0, Bs + off1);
            __syncthreads();
            bf16x8 af[4], bfm[4];
            #pragma unroll
            for (int mt = 0; mt < 4; ++mt)
                af[mt] = *(const bf16x8*)(As + (wm + (mt << 4) + l15) * 32 + (quad << 3));
            #pragma unroll
            for (int nt = 0; nt < 4; ++nt)
                bfm[nt] = *(const bf16x8*)(Bs + (wn + (nt << 4) + l15) * 32 + (quad << 3));
            #pragma unroll
            for (int mt = 0; mt < 4; ++mt)
                #pragma unroll
                for (int nt = 0; nt < 4; ++nt)
                    acc[mt][nt] = __builtin_amdgcn_mfma_f32_16x16x32_bf16(
                        af[mt], bfm[nt], acc[mt][nt], 0, 0, 0);
        }

        #pragma unroll
        for (int nt = 0; nt < 4; ++nt) {
            const int col = n0 + wn + (nt << 4) + l15;   // bt
            const int bi  = col >> 11;
            const int tt  = col & (TT - 1);
            #pragma unroll
            for (int mt = 0; mt < 4; ++mt) {
                #pragma unroll
                for (int reg = 0; reg < 4; ++reg) {
                    const int row = m0 + wm + (mt << 4) + (quad << 2) + reg;  // nh
                    float val = acc[mt][nt][reg] + bv[row];
                    oVt[((size_t)bi * 1024 + row) * TT + tt] = (bf16)val;
                }
            }
        }
    }
}

// ---------------------------------------------------------------------------
// Output projection GEMM: 128x64 tile, 512 blocks (2/CU), BK=32, fp32 out.
// ---------------------------------------------------------------------------
__global__ __launch_bounds__(256)
void gemm_out(const bf16* __restrict__ A, const bf16* __restrict__ Bt,
              const float* __restrict__ bias, float* __restrict__ oF)
{
    __shared__ bf16 As[128 * 32];
    __shared__ bf16 Bs[64 * 32];

    const int t    = threadIdx.x;
    const int lane = t & 63;
    const int w    = t >> 6;
    const int quad = lane >> 4, l15 = lane & 15;
    const int m0   = blockIdx.y << 7;
    const int n0   = blockIdx.x << 6;
    const int wm   = (w >> 1) << 6;
    const int wn   = (w & 1)  << 5;

    const int jr0 = ((w * 2 + 0) << 4) + (lane >> 2);
    const int jr1 = ((w * 2 + 1) << 4) + (lane >> 2);
    const int jrB = (w << 4) + (lane >> 2);
    const int kch = (lane & 3) << 3;

    bf16* lA0 = As + (w * 2 + 0) * 512;
    bf16* lA1 = As + (w * 2 + 1) * 512;
    bf16* lB  = Bs + w * 512;

    const bf16* Ap0 = A  + (size_t)(m0 + jr0) * DD + kch;
    const bf16* Ap1 = A  + (size_t)(m0 + jr1) * DD + kch;
    const bf16* Bp  = Bt + (size_t)(n0 + jrB) * DD + kch;

    f32x4 acc[4][2] = {};

    for (int k0 = 0; k0 < DD; k0 += 32) {
        __syncthreads();
        gld16(Ap0 + k0, lA0);
        gld16(Ap1 + k0, lA1);
        gld16(Bp + k0, lB);
        __syncthreads();
        bf16x8 af[4], bfm[2];
        #pragma unroll
        for (int mt = 0; mt < 4; ++mt)
            af[mt] = *(const bf16x8*)(As + (wm + (mt << 4) + l15) * 32 + (quad << 3));
        #pragma unroll
        for (int nt = 0; nt < 2; ++nt)
            bfm[nt] = *(const bf16x8*)(Bs + (wn + (nt << 4) + l15) * 32 + (quad << 3));
        #pragma unroll
        for (int mt = 0; mt < 4; ++mt)
            #pragma unroll
            for (int nt = 0; nt < 2; ++nt)
                acc[mt][nt] = __builtin_amdgcn_mfma_f32_16x16x32_bf16(
                    af[mt], bfm[nt], acc[mt][nt], 0, 0, 0);
    }

    #pragma unroll
    for (int nt = 0; nt < 2; ++nt) {
        const int col = n0 + wn + (nt << 4) + l15;
        const float bcol = bias[col];
        #pragma unroll
        for (int mt = 0; mt < 4; ++mt) {
            #pragma unroll
            for (int reg = 0; reg < 4; ++reg) {
                const int row = m0 + wm + (mt << 4) + (quad << 2) + reg;
                oF[(size_t)row * DD + col] = acc[mt][nt][reg] + bcol;
            }
        }
    }
}

// ---------------------------------------------------------------------------
// MFMA flash attention (512 thr, q-tile 128, 8 waves), DOUBLE-BUFFERED:
// one barrier per iter. Tile t+1's K/V/mask loads issue at iter top (HBM
// latency hides under tile t's MFMAs+softmax); staging writes to buf[cur^1]
// happen after PV; single barrier separates iterations. Reads of buf[cur]
// all precede the barrier; only buf[cur^1] is written in the same period.
// Mask folded into MFMA accumulator (lane-direct loads); row-sum via
// ones-row MFMA; swizzle (T2); setprio (T5); defer-max (T13).
// ---------------------------------------------------------------------------
__global__ __launch_bounds__(512, 4)
void attn_mfma(const bf16* __restrict__ Qh, const bf16* __restrict__ Ql,
               const bf16* __restrict__ Kh, const bf16* __restrict__ Kl,
               const bf16* __restrict__ Vt,
               const bf16* __restrict__ Madd,
               bf16* __restrict__ AO)
{
    __shared__ bf16 KH[2][64 * 64];
    __shared__ bf16 KL[2][64 * 64];
    __shared__ bf16 VS[2][64 * 64];    // [h][s], swizzled
    __shared__ bf16 PS[8][16 * 64];    // per-wave P, swizzled (same-wave RW)

    const int t    = threadIdx.x;
    const int lane = t & 63;
    const int w    = t >> 6;           // 0..7
    const int quad = lane >> 4, l15 = lane & 15;
    const int bn   = blockIdx.y;
    const int b    = bn >> 4, n = bn & 15;
    const int q0   = blockIdx.x << 7;  // 128 q per block

    const bf16* Qbh = Qh + (size_t)bn * TT * HD;
    const bf16* Qbl = Ql + (size_t)bn * TT * HD;
    const bf16* Kbh = Kh + (size_t)bn * TT * HD;
    const bf16* Kbl = Kl + (size_t)bn * TT * HD;
    const bf16* Vtb = Vt + (size_t)bn * HD * TT;
    const bf16* Mb  = Madd + (size_t)b * TT * TT;

    // Q fragments (B-operand: n=q=l15, k=h) — registers, loaded once
    const int qrow = q0 + (w << 4) + l15;
    bf16x8 qfh[2], qfl[2];
    qfh[0] = *(const bf16x8*)(Qbh + (size_t)qrow * HD + (quad << 3));
    qfh[1] = *(const bf16x8*)(Qbh + (size_t)qrow * HD + 32 + (quad << 3));
    qfl[0] = *(const bf16x8*)(Qbl + (size_t)qrow * HD + (quad << 3));
    qfl[1] = *(const bf16x8*)(Qbl + (size_t)qrow * HD + 32 + (quad << 3));

    f32x4 O[4];                         // O^T: row h=nt*16+quad*4+reg, col q=l15
    #pragma unroll
    for (int i = 0; i < 4; ++i) O[i] = (f32x4){0.f,0.f,0.f,0.f};
    f32x4 Ol = (f32x4){0.f,0.f,0.f,0.f};   // row-sum accumulator (ones-row)
    float m_i = -INFINITY;

    const bf16 onev = (bf16)1.0f;
    const bf16x8 ones = { onev, onev, onev, onev, onev, onev, onev, onev };

    // staging map: lane handles row rS, GLOBAL chunk (t&7); LDS write chunk
    // is XOR-swizzled so each 8-lane group fills one full 128B row.
    const int rS = t >> 3;                          // 0..63
    const int cG = (t & 7) << 3;                    // global elem offset
    const int cL = (((t & 7) ^ (rS & 7)) << 3);     // swizzled LDS offset
    // fragment-read swizzle key: row&7 == l15&7
    const int sw8 = (l15 & 7) << 3;

    // lane-direct mask base: this lane's q row, quad's 4-elem group
    const bf16* mrow0 = Mb + (size_t)qrow * TT + (quad << 2);

    // ---- prologue: stage tile 0 ----
    {
        bf16x8 khv = *(const bf16x8*)(Kbh + (size_t)rS * HD + cG);
        bf16x8 klv = *(const bf16x8*)(Kbl + (size_t)rS * HD + cG);
        bf16x8 vv  = *(const bf16x8*)(Vtb + (size_t)rS * TT + cG);
        *(bf16x8*)&KH[0][rS * 64 + cL] = khv;
        *(bf16x8*)&KL[0][rS * 64 + cL] = klv;
        *(bf16x8*)&VS[0][rS * 64 + cL] = vv;
    }
    ushort4 mu0 = *(const ushort4*)(mrow0);
    ushort4 mu1 = *(const ushort4*)(mrow0 + 16);
    ushort4 mu2 = *(const ushort4*)(mrow0 + 32);
    ushort4 mu3 = *(const ushort4*)(mrow0 + 48);
    __syncthreads();

    int cur = 0;
    for (int it = 0; it < 32; ++it) {
        const int last = (it == 31);
        // issue next tile's loads NOW — latency hides under this tile's work
        bf16x8 nkh, nkl, nvv;
        ushort4 nm0, nm1, nm2, nm3;
        if (!last) {
            const int kb2 = (it + 1) << 6;
            nkh = *(const bf16x8*)(Kbh + (size_t)(kb2 + rS) * HD + cG);
            nkl = *(const bf16x8*)(Kbl + (size_t)(kb2 + rS) * HD + cG);
            nvv = *(const bf16x8*)(Vtb + (size_t)rS * TT + kb2 + cG);
            const bf16* mr = mrow0 + kb2;
            nm0 = *(const ushort4*)(mr);
            nm1 = *(const ushort4*)(mr + 16);
            nm2 = *(const ushort4*)(mr + 32);
            nm3 = *(const ushort4*)(mr + 48);
        }

        const bf16* curKH = &KH[cur][0];
        const bf16* curKL = &KL[cur][0];
        const bf16* curVS = &VS[cur][0];

        // s_acc init = additive mask (C-in of the MFMA)
        f32x4 s_acc[4];
        s_acc[0][0] = __uint_as_float((unsigned)mu0.x << 16);
        s_acc[0][1] = __uint_as_float((unsigned)mu0.y << 16);
        s_acc[0][2] = __uint_as_float((unsigned)mu0.z << 16);
        s_acc[0][3] = __uint_as_float((unsigned)mu0.w << 16);
        s_acc[1][0] = __uint_as_float((unsigned)mu1.x << 16);
        s_acc[1][1] = __uint_as_float((unsigned)mu1.y << 16);
        s_acc[1][2] = __uint_as_float((unsigned)mu1.z << 16);
        s_acc[1][3] = __uint_as_float((unsigned)mu1.w << 16);
        s_acc[2][0] = __uint_as_float((unsigned)mu2.x << 16);
        s_acc[2][1] = __uint_as_float((unsigned)mu2.y << 16);
        s_acc[2][2] = __uint_as_float((unsigned)mu2.z << 16);
        s_acc[2][3] = __uint_as_float((unsigned)mu2.w << 16);
        s_acc[3][0] = __uint_as_float((unsigned)mu3.x << 16);
        s_acc[3][1] = __uint_as_float((unsigned)mu3.y << 16);
        s_acc[3][2] = __uint_as_float((unsigned)mu3.z << 16);
        s_acc[3][3] = __uint_as_float((unsigned)mu3.w << 16);

        // S^T = K Q^T + M (rows s, cols q), split: Kh*Qh + Kl*Qh + Kh*Ql
        __builtin_amdgcn_s_setprio(1);
        #pragma unroll
        for (int k2 = 0; k2 < 2; ++k2) {
            #pragma unroll
            for (int nt = 0; nt < 4; ++nt) {
                const int ro = ((nt << 4) + l15) * 64;
                const int co = ((k2 << 5) + (quad << 3)) ^ sw8;
                bf16x8 bkh = *(const bf16x8*)&curKH[ro + co];
                bf16x8 bkl = *(const bf16x8*)&curKL[ro + co];
                s_acc[nt] = __builtin_amdgcn_mfma_f32_16x16x32_bf16(bkh, qfh[k2], s_acc[nt], 0, 0, 0);
                s_acc[nt] = __builtin_amdgcn_mfma_f32_16x16x32_bf16(bkl, qfh[k2], s_acc[nt], 0, 0, 0);
                s_acc[nt] = __builtin_amdgcn_mfma_f32_16x16x32_bf16(bkh, qfl[k2], s_acc[nt], 0, 0, 0);
            }
        }
        __builtin_amdgcn_s_setprio(0);

        // per-lane softmax over s — mask already inside s_acc.
        float t0 = fmaxf(fmaxf(s_acc[0][0], s_acc[0][1]), s_acc[0][2]);
        float t1 = fmaxf(fmaxf(s_acc[0][3], s_acc[1][0]), s_acc[1][1]);
        float t2 = fmaxf(fmaxf(s_acc[1][2], s_acc[1][3]), s_acc[2][0]);
        float t3 = fmaxf(fmaxf(s_acc[2][1], s_acc[2][2]), s_acc[2][3]);
        float t4 = fmaxf(fmaxf(s_acc[3][0], s_acc[3][1]), s_acc[3][2]);
        float mx = fmaxf(fmaxf(fmaxf(t0, t1), t2),
                         fmaxf(fmaxf(t3, t4), s_acc[3][3]));
        mx = fmaxf(mx, __shfl_xor(mx, 16));
        mx = fmaxf(mx, __shfl_xor(mx, 32));

        // T13 defer-max (exp2 domain, THR=8); Ol rescales with O
        if (!__all(mx <= m_i + 8.0f)) {
            const float mnew  = fmaxf(m_i, mx);
            const float alpha = exp2f(m_i - mnew);   // exp2(-inf)=0 first tile
            #pragma unroll
            for (int nt = 0; nt < 4; ++nt) {
                O[nt][0] *= alpha; O[nt][1] *= alpha;
                O[nt][2] *= alpha; O[nt][3] *= alpha;
            }
            Ol[0] *= alpha; Ol[1] *= alpha; Ol[2] *= alpha; Ol[3] *= alpha;
            m_i = mnew;
        }

        float p[16];
        #pragma unroll
        for (int nt = 0; nt < 4; ++nt)
            #pragma unroll
            for (int reg = 0; reg < 4; ++reg)
                p[nt * 4 + reg] = exp2f(s_acc[nt][reg] - m_i);  // masked -> 0

        #pragma unroll
        for (int nt = 0; nt < 4; ++nt) {
            bf16x4 pv = { (bf16)p[nt * 4 + 0], (bf16)p[nt * 4 + 1],
                          (bf16)p[nt * 4 + 2], (bf16)p[nt * 4 + 3] };
            *(bf16x4*)&PS[w][l15 * 64 + (((nt << 4) + (quad << 2)) ^ sw8)] = pv;
        }

        // O^T += Vt P^T  (A=Vt rows h, B=P rows q); ones-row MFMA -> row sums
        __builtin_amdgcn_s_setprio(1);
        #pragma unroll
        for (int s2i = 0; s2i < 2; ++s2i) {
            bf16x8 ap = *(const bf16x8*)&PS[w][l15 * 64 + (((s2i << 5) + (quad << 3)) ^ sw8)];
            Ol = __builtin_amdgcn_mfma_f32_16x16x32_bf16(ones, ap, Ol, 0, 0, 0);
            #pragma unroll
            for (int nt = 0; nt < 4; ++nt) {
                bf16x8 bv = *(const bf16x8*)&curVS[((nt << 4) + l15) * 64
                                                   + (((s2i << 5) + (quad << 3)) ^ sw8)];
                O[nt] = __builtin_amdgcn_mfma_f32_16x16x32_bf16(bv, ap, O[nt], 0, 0, 0);
            }
        }
        __builtin_amdgcn_s_setprio(0);

        // stage next tile into the other buffer; rotate mask regs
        if (!last) {
            const int nxt = cur ^ 1;
            *(bf16x8*)&KH[nxt][rS * 64 + cL] = nkh;
            *(bf16x8*)&KL[nxt][rS * 64 + cL] = nkl;
            *(bf16x8*)&VS[nxt][rS * 64 + cL] = nvv;
            mu0 = nm0; mu1 = nm1; mu2 = nm2; mu3 = nm3;
            __syncthreads();   // writes visible; all reads of buf[cur] done
            cur = nxt;
        }
    }

    // normalize + write AO (bf16, [B*T][N*H]); lane owns col q, rows h.
    // Ol regs all equal Σ_s p[s][q=l15] — every lane holds its own l.
    {
        const float inv = 1.0f / Ol[0];
        const size_t base = ((size_t)b * TT + qrow) * (NHD * HD) + (size_t)n * HD;
        #pragma unroll
        for (int nt = 0; nt < 4; ++nt) {
            bf16x4 o = { (bf16)(O[nt][0] * inv), (bf16)(O[nt][1] * inv),
                         (bf16)(O[nt][2] * inv), (bf16)(O[nt][3] * inv) };
            *(bf16x4*)(AO + base + (nt << 4) + (quad << 2)) = o;
        }
    }
}

// ---------------------------------------------------------------------------
extern "C" void kernel_launch(void* const* d_in, const int* in_sizes, int n_in,
                              void* d_out, int out_size, void* d_ws, size_t ws_size,
                              hipStream_t stream)
{
    const float* X   = (const float*)d_in[0];
    const int*   msk = (const int*)d_in[1];
    const float* wq  = (const float*)d_in[2];
    const float* bq  = (const float*)d_in[3];
    const float* wk  = (const float*)d_in[4];
    const float* bk  = (const float*)d_in[5];
    const float* wv  = (const float*)d_in[6];
    const float* bv  = (const float*)d_in[7];
    const float* wo  = (const float*)d_in[8];
    const float* bo  = (const float*)d_in[9];
    const float* pds = (const float*)d_in[10];
    float* out = (float*)d_out;

    bf16* ws   = (bf16*)d_ws;
    bf16* Xh   = ws;                      // 4M  (later aliased by AO)
    bf16* Xl   = ws + 4194304;            // 4M
    bf16* WQKh = ws + 8388608;            // 2M  [2048 nh'][1024 d]
    bf16* WQKl = ws + 10485760;           // 2M
    bf16* Wvh  = ws + 12582912;           // 1M  [nh][d]
    bf16* Wob  = ws + 13631488;           // 1M  [d][nh]
    bf16* Qhb  = ws + 14680064;           // 4M  [b][n][t][h]
    bf16* Qlb  = ws + 18874368;
    bf16* Khb  = ws + 23068672;
    bf16* Klb  = ws + 27262976;
    bf16* Vtb  = ws + 32505856;           // 4M [b][nh][t]
    bf16* AOb  = Xh;                      // alias: Xh dead after proj
    // additive mask lives in d_out (16 MB = out_size exactly); it is consumed
    // by attn_mfma BEFORE gemm_out overwrites d_out with the final result.
    bf16* madd = (bf16*)d_out;

    dim3 blk(256);

    prep_all<<<12288, blk, 0, stream>>>(X, msk, wq, wk, wv, wo,
                                        Xh, Xl, WQKh, WQKl, Wvh, Wob, madd);

    // fused QK + V projections
    gemm_proj<<<768, blk, 0, stream>>>(
        Xh, Xl, WQKh, WQKl, Wvh, bq, bk, bv, pds,
        Qhb, Qlb, Khb, Klb, Vtb);

    dim3 ga(TT / 128, BB * NHD);   // (16, 32)
    attn_mfma<<<ga, dim3(512), 0, stream>>>(
        Qhb, Qlb, Khb, Klb, Vtb, madd, AOb);

    // output projection: M=4096, N=1024, K=1024, fp32 out, 128x64 tiles
    gemm_out<<<dim3(16, 32), blk, 0, stream>>>(AOb, Wob, bo, out);
}